// Round 1
// 669.852 us; speedup vs baseline: 1.7283x; 1.7283x over previous
//
#include <hip/hip_runtime.h>

typedef unsigned short u16;
typedef short s8v __attribute__((ext_vector_type(8)));
typedef float f4v __attribute__((ext_vector_type(4)));

#define AS1 __attribute__((address_space(1)))
#define AS3 __attribute__((address_space(3)))

__device__ __forceinline__ float bf2f(u16 u) {
    union { unsigned int i; float f; } x; x.i = ((unsigned int)u) << 16; return x.f;
}
__device__ __forceinline__ u16 f2bf(float f) {
    union { float f; unsigned int i; } x; x.f = f;
    unsigned int r = x.i + 0x7fffu + ((x.i >> 16) & 1u);
    return (u16)(r >> 16);
}

// async global->LDS, 16B per lane; LDS dest = wave-uniform base + lane*16
__device__ __forceinline__ void glds16(const u16* g, u16* l) {
    __builtin_amdgcn_global_load_lds((AS1 void*)(g), (AS3 void*)(l), 16, 0, 0);
}

// ---------------------------------------------------------------------------
// Weight convert+transpose: W f32 [K][N] -> WT bf16 [N][K]. Batched over z.
// ---------------------------------------------------------------------------
__global__ __launch_bounds__(256) void convT_k(const float* __restrict__ W,
        u16* __restrict__ WT, int N, int K)
{
    const size_t mat = (size_t)blockIdx.z * K * N;
    const int n0 = blockIdx.x * 64, k0 = blockIdx.y * 64;
    __shared__ float t[64][65];
    const int r = threadIdx.x >> 2;          // 0..63
    const int c = (threadIdx.x & 3) << 4;    // 0,16,32,48
    const float* wp = W + mat + (size_t)(k0 + r) * N + n0 + c;
    #pragma unroll
    for (int q = 0; q < 16; q += 4) {
        float4 f = *(const float4*)(wp + q);
        t[c + q + 0][r] = f.x; t[c + q + 1][r] = f.y;
        t[c + q + 2][r] = f.z; t[c + q + 3][r] = f.w;
    }
    __syncthreads();
    u16* op = WT + mat + (size_t)(n0 + r) * K + k0 + c;
    #pragma unroll
    for (int q = 0; q < 16; q += 8) {
        s8v v;
        #pragma unroll
        for (int j = 0; j < 8; ++j) v[j] = (short)f2bf(t[r][c + q + j]);
        *(s8v*)(op + q) = v;
    }
}

// ---------------------------------------------------------------------------
// Elementwise f32 -> bf16 (8 per thread). n8 = elems/8.
// ---------------------------------------------------------------------------
__global__ __launch_bounds__(256) void conv_k(const float* __restrict__ in,
        u16* __restrict__ out, int n8)
{
    const int i = blockIdx.x * 256 + threadIdx.x;
    if (i >= n8) return;
    const float4 f0 = ((const float4*)in)[i * 2];
    const float4 f1 = ((const float4*)in)[i * 2 + 1];
    s8v v;
    v[0]=(short)f2bf(f0.x); v[1]=(short)f2bf(f0.y);
    v[2]=(short)f2bf(f0.z); v[3]=(short)f2bf(f0.w);
    v[4]=(short)f2bf(f1.x); v[5]=(short)f2bf(f1.y);
    v[6]=(short)f2bf(f1.z); v[7]=(short)f2bf(f1.w);
    ((s8v*)out)[i] = v;
}

// ---------------------------------------------------------------------------
// Batched m97-structure bf16 GEMM: out[z] = epi(A[z] @ WT[z]^T).
// 128x128 tile, BK=64, 4 waves, 4x4 16x16 frags/wave, global_load_lds(16B).
// Per-z epilogue: experts -> +bias (LN done separately); z==zdom -> BN+ReLU.
// M,N,K multiples of 128/128/64. Grid (N/128, M/128, Z).
// ---------------------------------------------------------------------------
template<int HASDOM>
__global__ __launch_bounds__(256) void gemm_bt128_k(
    const u16* __restrict__ A0, size_t aStrideZ,
    const u16* __restrict__ WT0,
    const float* __restrict__ ebias,                       // [Z][N] expert bias
    const float* __restrict__ dbias, const float* __restrict__ dgam,
    const float* __restrict__ dbet,  const float* __restrict__ dmean,
    const float* __restrict__ dvar,  int zdom,
    u16* __restrict__ out0, int M, int N, int K)
{
    const int z = blockIdx.z;
    const u16* A  = A0  + (size_t)z * aStrideZ;
    const u16* WT = WT0 + (size_t)z * N * K;
    u16* out = out0 + (size_t)z * M * N;

    const int n0 = blockIdx.x * 128, m0 = blockIdx.y * 128;
    const int t = threadIdx.x;
    const int w = t >> 6, lane = t & 63;
    const int lq = lane >> 4, lr = lane & 15;
    const int wm = (w >> 1) * 64, wn = (w & 1) * 64;

    __shared__ __align__(16) u16 As[128 * 64];   // [m][k]
    __shared__ __align__(16) u16 Bs[128 * 64];   // [n][k]

    f4v acc[4][4] = {};

    // staging: thread t, issue q: LDS byte off = q*4096 + t*16  (= row*128 + chunk*16)
    //   row = q*32 + (t>>3), chunk = t&7.  Wave-uniform LDS base + lane*16 holds. 
    const u16* ga = A  + (size_t)(m0 + (t >> 3)) * K + ((t & 7) << 3);
    const u16* gb = WT + (size_t)(n0 + (t >> 3)) * K + ((t & 7) << 3);
    const int ldsb = w * 512;   // elements

    for (int kk = 0; kk < K; kk += 64) {
        #pragma unroll
        for (int q = 0; q < 4; ++q) {
            glds16(ga + kk + (size_t)q * 32 * K, &As[q * 2048 + ldsb]);
            glds16(gb + kk + (size_t)q * 32 * K, &Bs[q * 2048 + ldsb]);
        }
        __syncthreads();   // drains vmcnt before barrier
        #pragma unroll
        for (int ks = 0; ks < 64; ks += 32) {
            const int kq = ks + (lq << 3);
            s8v a[4], b[4];
            #pragma unroll
            for (int i = 0; i < 4; ++i) a[i] = *(const s8v*)&As[(wm + i*16 + lr) * 64 + kq];
            #pragma unroll
            for (int j = 0; j < 4; ++j) b[j] = *(const s8v*)&Bs[(wn + j*16 + lr) * 64 + kq];
            #pragma unroll
            for (int i = 0; i < 4; ++i)
                #pragma unroll
                for (int j = 0; j < 4; ++j)
                    acc[i][j] = __builtin_amdgcn_mfma_f32_16x16x32_bf16(a[i], b[j], acc[i][j], 0, 0, 0);
        }
        __syncthreads();
    }

    // epilogue: frag D mapping col=lane&15, row=(lane>>4)*4+r
    float scale[4], shift[4];
    const bool dom = HASDOM && (z == zdom);
    #pragma unroll
    for (int j = 0; j < 4; ++j) {
        const int c = n0 + wn + j * 16 + lr;
        if (dom) {
            const float s = dgam[c] / sqrtf(dvar[c] + 1e-5f);
            scale[j] = s;
            shift[j] = (dbias[c] - dmean[c]) * s + dbet[c];
        } else {
            scale[j] = 1.f;
            shift[j] = ebias[(size_t)z * N + c];
        }
    }
    const int r0 = lq << 2;
    #pragma unroll
    for (int i = 0; i < 4; ++i) {
        #pragma unroll
        for (int r = 0; r < 4; ++r) {
            const int grow = m0 + wm + i * 16 + r0 + r;
            u16* orow = out + (size_t)grow * N + n0 + wn + lr;
            #pragma unroll
            for (int j = 0; j < 4; ++j) {
                float y = fmaf(acc[i][j][r], scale[j], shift[j]);
                if (dom) y = fmaxf(y, 0.f);
                orow[j * 16] = f2bf(y);
            }
        }
    }
}

// ---------------------------------------------------------------------------
// f32-exact split-K GEMM (routing h1 partials, no epilogue).
// Grid (N/64, M/64, 4); slice z covers K range [z*Ks, (z+1)*Ks).
// ---------------------------------------------------------------------------
__global__ __launch_bounds__(256) void gemm_f32sk_k(
    const float* __restrict__ A, const float* __restrict__ W,
    float* __restrict__ out, int M, int N, int K, int Ks)
{
    const int n0 = blockIdx.x * 64, m0 = blockIdx.y * 64;
    const int kb = blockIdx.z * Ks;
    out += (size_t)blockIdx.z * M * N;
    const int tid = threadIdx.x;
    const int tx = tid & 15, ty = tid >> 4;
    __shared__ float As[64][65];
    __shared__ float Bs[64][64];
    float acc[4][4] = {};
    const int sr = tid >> 2;
    const int sc = (tid & 3) << 4;
    for (int kk = kb; kk < kb + Ks; kk += 64) {
        const float* ap = A + (size_t)(m0 + sr) * K + kk + sc;
        #pragma unroll
        for (int q = 0; q < 4; ++q) {
            float4 f = *(const float4*)(ap + q * 4);
            As[sr][sc + q*4 + 0] = f.x; As[sr][sc + q*4 + 1] = f.y;
            As[sr][sc + q*4 + 2] = f.z; As[sr][sc + q*4 + 3] = f.w;
        }
        const float* wp = W + (size_t)(kk + sr) * N + n0 + sc;
        #pragma unroll
        for (int q = 0; q < 4; ++q)
            *(float4*)&Bs[sr][sc + q*4] = *(const float4*)(wp + q * 4);
        __syncthreads();
        #pragma unroll 4
        for (int kq = 0; kq < 64; ++kq) {
            float a[4], bv[4];
            #pragma unroll
            for (int i = 0; i < 4; ++i) a[i] = As[ty*4 + i][kq];
            #pragma unroll
            for (int j = 0; j < 4; ++j) bv[j] = Bs[kq][tx*4 + j];
            #pragma unroll
            for (int i = 0; i < 4; ++i)
                #pragma unroll
                for (int j = 0; j < 4; ++j)
                    acc[i][j] = fmaf(a[i], bv[j], acc[i][j]);
        }
        __syncthreads();
    }
    #pragma unroll
    for (int j = 0; j < 4; ++j) {
        const int c = n0 + tx*4 + j;
        #pragma unroll
        for (int i = 0; i < 4; ++i)
            out[(size_t)(m0 + ty*4 + i) * N + c] = acc[i][j];
    }
}

// ---------------------------------------------------------------------------
// Fused routing tail: combine 4 K-partials + BN1 + ReLU -> h2 GEMM + BN2 +
// ReLU -> classifier + log_softmax + argmax. 4 samples/block (bw2 reuse x4).
// ---------------------------------------------------------------------------
__global__ __launch_bounds__(256) void h2cls_k(
    const float* __restrict__ hp,   // [4][B][512] raw partial sums
    const float* __restrict__ bb1, const float* __restrict__ bg1,
    const float* __restrict__ bbe1, const float* __restrict__ bm1,
    const float* __restrict__ bv1,
    const float* __restrict__ bw2, const float* __restrict__ bb2,
    const float* __restrict__ bg2, const float* __restrict__ bbe2,
    const float* __restrict__ bm2, const float* __restrict__ bv2,
    const float* __restrict__ cw,  const float* __restrict__ cb,
    float* __restrict__ out_src, int* __restrict__ label, int B)
{
    const int b0 = blockIdx.x * 4;
    const int t = threadIdx.x;
    const size_t sl = (size_t)B * 512;
    __shared__ float h1s[4][512];
    __shared__ float h2s[4][256];

    #pragma unroll
    for (int cc = 0; cc < 2; ++cc) {
        const int c = t + cc * 256;
        const float sc = bg1[c] / sqrtf(bv1[c] + 1e-5f);
        const float sh = (bb1[c] - bm1[c]) * sc + bbe1[c];
        #pragma unroll
        for (int s = 0; s < 4; ++s) {
            const size_t ix = (size_t)(b0 + s) * 512 + c;
            const float v = hp[ix] + hp[ix + sl] + hp[ix + 2*sl] + hp[ix + 3*sl];
            h1s[s][c] = fmaxf(fmaf(v, sc, sh), 0.f);
        }
    }
    __syncthreads();

    float acc[4] = {};
    #pragma unroll 4
    for (int k = 0; k < 512; ++k) {
        const float wv = bw2[(size_t)k * 256 + t];
        #pragma unroll
        for (int s = 0; s < 4; ++s) acc[s] = fmaf(h1s[s][k], wv, acc[s]);
    }
    const float sc2 = bg2[t] / sqrtf(bv2[t] + 1e-5f);
    const float sh2 = (bb2[t] - bm2[t]) * sc2 + bbe2[t];
    #pragma unroll
    for (int s = 0; s < 4; ++s) h2s[s][t] = fmaxf(fmaf(acc[s], sc2, sh2), 0.f);
    __syncthreads();

    // one wave per sample
    const int s = t >> 6, lane = t & 63;
    float p[8] = {};
    for (int k = lane; k < 256; k += 64) {
        const float x = h2s[s][k];
        #pragma unroll
        for (int c = 0; c < 8; ++c) p[c] = fmaf(x, cw[k * 8 + c], p[c]);
    }
    #pragma unroll
    for (int off = 32; off; off >>= 1)
        #pragma unroll
        for (int c = 0; c < 8; ++c) p[c] += __shfl_xor(p[c], off, 64);
    if (lane == 0) {
        const int b = b0 + s;
        float lg[8];
        #pragma unroll
        for (int c = 0; c < 8; ++c) lg[c] = p[c] + cb[c];
        float mx = lg[0]; int am = 0;
        #pragma unroll
        for (int c = 1; c < 8; ++c) if (lg[c] > mx) { mx = lg[c]; am = c; }
        float ssum = 0.f;
        #pragma unroll
        for (int c = 0; c < 8; ++c) ssum += expf(lg[c] - mx);
        const float lse = mx + logf(ssum);
        #pragma unroll
        for (int c = 0; c < 8; ++c) out_src[b * 8 + c] = lg[c] - lse;
        label[b] = am;
    }
}

// ---------------------------------------------------------------------------
// In-place LayerNorm + ReLU, batched over z (grid.y), N in {512,1024}.
// ---------------------------------------------------------------------------
template<int N>
__global__ __launch_bounds__(256) void ln_relu_k(u16* __restrict__ Y,
        const float* __restrict__ g, const float* __restrict__ bb)
{
    const int z = blockIdx.y;
    u16* y = Y + ((size_t)z * gridDim.x + blockIdx.x) * N;
    const float* gz = g  + (size_t)z * N;
    const float* bz = bb + (size_t)z * N;
    const int t = threadIdx.x;
    constexpr int C = N >> 8;   // 4 or 2
    float vals[C];
    if (C == 4) {
        ushort4 u = ((const ushort4*)y)[t];
        vals[0] = bf2f(u.x); vals[1] = bf2f(u.y);
        vals[2] = bf2f(u.z); vals[3] = bf2f(u.w);
    } else {
        ushort2 u = ((const ushort2*)y)[t];
        vals[0] = bf2f(u.x); vals[1] = bf2f(u.y);
    }
    float s = 0.f, sq = 0.f;
    #pragma unroll
    for (int i = 0; i < C; ++i) { s += vals[i]; sq += vals[i] * vals[i]; }
    #pragma unroll
    for (int off = 32; off; off >>= 1) {
        s  += __shfl_xor(s,  off, 64);
        sq += __shfl_xor(sq, off, 64);
    }
    __shared__ float rs[4], rq[4];
    if ((t & 63) == 0) { rs[t >> 6] = s; rq[t >> 6] = sq; }
    __syncthreads();
    s  = rs[0] + rs[1] + rs[2] + rs[3];
    sq = rq[0] + rq[1] + rq[2] + rq[3];
    const float inv = 1.f / (float)N;
    const float mu  = s * inv;
    const float var = sq * inv - mu * mu;
    const float rstd = rsqrtf(var + 1e-5f);
    if (C == 4) {
        float4 gv = ((const float4*)gz)[t];
        float4 bv = ((const float4*)bz)[t];
        ushort4 o;
        o.x = f2bf(fmaxf((vals[0] - mu) * rstd * gv.x + bv.x, 0.f));
        o.y = f2bf(fmaxf((vals[1] - mu) * rstd * gv.y + bv.y, 0.f));
        o.z = f2bf(fmaxf((vals[2] - mu) * rstd * gv.z + bv.z, 0.f));
        o.w = f2bf(fmaxf((vals[3] - mu) * rstd * gv.w + bv.w, 0.f));
        ((ushort4*)y)[t] = o;
    } else {
        float2 gv = ((const float2*)gz)[t];
        float2 bv = ((const float2*)bz)[t];
        ushort2 o;
        o.x = f2bf(fmaxf((vals[0] - mu) * rstd * gv.x + bv.x, 0.f));
        o.y = f2bf(fmaxf((vals[1] - mu) * rstd * gv.y + bv.y, 0.f));
        ((ushort2*)y)[t] = o;
    }
}

// ---------------------------------------------------------------------------
// 2-class head + log_softmax, batched over z (grid.y). 1 wave/row.
// ---------------------------------------------------------------------------
__global__ __launch_bounds__(64) void head2_k(const u16* __restrict__ X, size_t xsz,
        const float* __restrict__ W, size_t wsz,
        const float* __restrict__ bias, size_t bsz,
        int K, float* __restrict__ out, size_t osz)
{
    const int b = blockIdx.x, z = blockIdx.y;
    const int lane = threadIdx.x;
    const u16* x = X + z * xsz + (size_t)b * K;
    const float* Wz = W + z * wsz;
    const float* bz = bias + z * bsz;
    float* o = out + z * osz + (size_t)b * 2;
    float p0 = 0.f, p1 = 0.f;
    for (int k = lane; k < K; k += 64) {
        const float xv = bf2f(x[k]);
        p0 = fmaf(xv, Wz[k * 2],     p0);
        p1 = fmaf(xv, Wz[k * 2 + 1], p1);
    }
    #pragma unroll
    for (int off = 32; off; off >>= 1) {
        p0 += __shfl_xor(p0, off, 64);
        p1 += __shfl_xor(p1, off, 64);
    }
    if (lane == 0) {
        const float l0 = p0 + bz[0];
        const float l1 = p1 + bz[1];
        const float mx = fmaxf(l0, l1);
        const float lse = mx + logf(expf(l0 - mx) + expf(l1 - mx));
        o[0] = l0 - lse;
        o[1] = l1 - lse;
    }
}

__global__ __launch_bounds__(256) void gather_k(const float* __restrict__ eo,
        const int* __restrict__ label, float* __restrict__ out, int B)
{
    const int b = blockIdx.x * 256 + threadIdx.x;
    if (b >= B) return;
    const int e = label[b];
    out[b * 2]     = eo[((size_t)e * B + b) * 2];
    out[b * 2 + 1] = eo[((size_t)e * B + b) * 2 + 1];
}

__global__ __launch_bounds__(256) void copy16_k(const uint4* __restrict__ in,
                                                uint4* __restrict__ out, int n16)
{
    const int i = blockIdx.x * blockDim.x + threadIdx.x;
    if (i < n16) out[i] = in[i];
}

// ---------------------------------------------------------------------------

extern "C" void kernel_launch(void* const* d_in, const int* in_sizes, int n_in,
                              void* d_out, int out_size, void* d_ws, size_t ws_size,
                              hipStream_t stream)
{
    const int B = 2048, D = 1280, E = 8;

    const float* src = (const float*)d_in[0];
    const float *bw1 = (const float*)d_in[1],  *bb1 = (const float*)d_in[2],
                *bg1 = (const float*)d_in[3],  *bbe1 = (const float*)d_in[4],
                *bm1 = (const float*)d_in[5],  *bv1 = (const float*)d_in[6];
    const float *bw2 = (const float*)d_in[7],  *bb2 = (const float*)d_in[8],
                *bg2 = (const float*)d_in[9],  *bbe2 = (const float*)d_in[10],
                *bm2 = (const float*)d_in[11], *bv2 = (const float*)d_in[12];
    const float *cw  = (const float*)d_in[13], *cb  = (const float*)d_in[14];
    const float *dw1 = (const float*)d_in[15], *db1 = (const float*)d_in[16],
                *dg1 = (const float*)d_in[17], *dbe1 = (const float*)d_in[18],
                *dm1 = (const float*)d_in[19], *dv1 = (const float*)d_in[20];
    const float *dw2 = (const float*)d_in[21], *db2 = (const float*)d_in[22],
                *dg2 = (const float*)d_in[23], *dbe2 = (const float*)d_in[24],
                *dm2 = (const float*)d_in[25], *dv2 = (const float*)d_in[26];
    const float *dw3 = (const float*)d_in[27], *db3 = (const float*)d_in[28],
                *dg3 = (const float*)d_in[29], *dbe3 = (const float*)d_in[30],
                *dm3 = (const float*)d_in[31], *dv3 = (const float*)d_in[32];
    const float *dw4 = (const float*)d_in[33], *db4 = (const float*)d_in[34];
    const float *ew1 = (const float*)d_in[35], *eb1 = (const float*)d_in[36],
                *eg1 = (const float*)d_in[37], *ebe1 = (const float*)d_in[38];
    const float *ew2 = (const float*)d_in[39], *eb2 = (const float*)d_in[40],
                *eg2 = (const float*)d_in[41], *ebe2 = (const float*)d_in[42];
    const float *ew3 = (const float*)d_in[43], *eb3 = (const float*)d_in[44],
                *eg3 = (const float*)d_in[45], *ebe3 = (const float*)d_in[46];
    const float *ew4 = (const float*)d_in[47], *eb4 = (const float*)d_in[48];

    float* out_src   = (float*)d_out;
    float* out_dclf  = out_src + B * E;
    float* out_sout  = out_dclf + B * 2;
    float* out_share = out_sout + B * 2;

    // ws layout (peak 60.44 MB < 65.67 MB proven):
    //   wslot [0, 13.11M)       bf16, JIT-transposed weights, up to 5 x 1024x1280
    //   srcb  [13.11M, 18.35M)  bf16 [2048][1280]
    //   acta  [18.35M, 39.32M)  bf16 5 x [2048][1024]   (hp f32 [4][2048][512] overlaps, routing-only)
    //   actb  [39.32M, 60.29M)  bf16 5 x [2048][1024]
    //   eo    [60.29M, +128K) ; label [+8K)
    char* ws = (char*)d_ws;
    u16*   wslot = (u16*)ws;
    u16*   srcb  = (u16*)(ws + 13107200);
    u16*   acta  = (u16*)(ws + 18350080);
    u16*   actb  = (u16*)(ws + 39321600);
    float* eo    = (float*)(ws + 60293120);
    int*   label = (int*)(ws + 60424192);
    float* hp    = (float*)(ws + 18350080);   // overlaps acta; dead before experts

    const size_t s1024 = (size_t)B * 1024, s512 = (size_t)B * 512;

    // ---- src conversion + share passthrough ----
    conv_k<<<dim3(B * D / 8 / 256), 256, 0, stream>>>(src, srcb, B * D / 8);
    copy16_k<<<dim3(B * D * 4 / 16 / 256), 256, 0, stream>>>(
        (const uint4*)src, (uint4*)out_share, B * D * 4 / 16);

    // ---- routing: split-K=4 f32 GEMM -> fused combine/BN/h2/classifier ----
    gemm_f32sk_k<<<dim3(512 / 64, B / 64, 4), 256, 0, stream>>>(
        src, bw1, hp, B, 512, D, 320);
    h2cls_k<<<dim3(B / 4), 256, 0, stream>>>(
        hp, bb1, bg1, bbe1, bm1, bv1, bw2, bb2, bg2, bbe2, bm2, bv2,
        cw, cb, out_src, label, B);

    // ---- group A: experts 0..3 + domain classifier as z=4 ----
    convT_k<<<dim3(16, 20, 4), 256, 0, stream>>>(ew1, wslot, 1024, 1280);
    convT_k<<<dim3(16, 20, 1), 256, 0, stream>>>(dw1, wslot + (size_t)4*1024*1280, 1024, 1280);
    gemm_bt128_k<1><<<dim3(8, 16, 5), 256, 0, stream>>>(
        srcb, 0, wslot, eb1, db1, dg1, dbe1, dm1, dv1, 4, acta, B, 1024, 1280);
    ln_relu_k<1024><<<dim3(B, 4), 256, 0, stream>>>(acta, eg1, ebe1);

    convT_k<<<dim3(16, 16, 4), 256, 0, stream>>>(ew2, wslot, 1024, 1024);
    convT_k<<<dim3(16, 16, 1), 256, 0, stream>>>(dw2, wslot + (size_t)4*1024*1024, 1024, 1024);
    gemm_bt128_k<1><<<dim3(8, 16, 5), 256, 0, stream>>>(
        acta, s1024, wslot, eb2, db2, dg2, dbe2, dm2, dv2, 4, actb, B, 1024, 1024);
    ln_relu_k<1024><<<dim3(B, 4), 256, 0, stream>>>(actb, eg2, ebe2);

    convT_k<<<dim3(8, 16, 4), 256, 0, stream>>>(ew3, wslot, 512, 1024);
    convT_k<<<dim3(8, 16, 1), 256, 0, stream>>>(dw3, wslot + (size_t)4*512*1024, 512, 1024);
    gemm_bt128_k<1><<<dim3(4, 16, 5), 256, 0, stream>>>(
        actb, s1024, wslot, eb3, db3, dg3, dbe3, dm3, dv3, 4, acta, B, 512, 1024);
    ln_relu_k<512><<<dim3(B, 4), 256, 0, stream>>>(acta, eg3, ebe3);

    head2_k<<<dim3(B, 4), 64, 0, stream>>>(
        acta, s512, ew4, 1024, eb4, 2, 512, eo, (size_t)B * 2);
    head2_k<<<dim3(B, 1), 64, 0, stream>>>(
        acta + (size_t)4 * B * 512, 0, dw4, 0, db4, 0, 512, out_dclf, 0);

    // ---- group B: experts 4..7 ----
    convT_k<<<dim3(16, 20, 4), 256, 0, stream>>>(ew1 + (size_t)4*1280*1024, wslot, 1024, 1280);
    gemm_bt128_k<0><<<dim3(8, 16, 4), 256, 0, stream>>>(
        srcb, 0, wslot, eb1 + (size_t)4*1024,
        nullptr, nullptr, nullptr, nullptr, nullptr, -1, acta, B, 1024, 1280);
    ln_relu_k<1024><<<dim3(B, 4), 256, 0, stream>>>(acta, eg1 + (size_t)4*1024, ebe1 + (size_t)4*1024);

    convT_k<<<dim3(16, 16, 4), 256, 0, stream>>>(ew2 + (size_t)4*1024*1024, wslot, 1024, 1024);
    gemm_bt128_k<0><<<dim3(8, 16, 4), 256, 0, stream>>>(
        acta, s1024, wslot, eb2 + (size_t)4*1024,
        nullptr, nullptr, nullptr, nullptr, nullptr, -1, actb, B, 1024, 1024);
    ln_relu_k<1024><<<dim3(B, 4), 256, 0, stream>>>(actb, eg2 + (size_t)4*1024, ebe2 + (size_t)4*1024);

    convT_k<<<dim3(8, 16, 4), 256, 0, stream>>>(ew3 + (size_t)4*1024*512, wslot, 512, 1024);
    gemm_bt128_k<0><<<dim3(4, 16, 4), 256, 0, stream>>>(
        actb, s1024, wslot, eb3 + (size_t)4*512,
        nullptr, nullptr, nullptr, nullptr, nullptr, -1, acta, B, 512, 1024);
    ln_relu_k<512><<<dim3(B, 4), 256, 0, stream>>>(acta, eg3 + (size_t)4*512, ebe3 + (size_t)4*512);

    head2_k<<<dim3(B, 4), 64, 0, stream>>>(
        acta, s512, ew4 + (size_t)4*512*2, 1024, eb4 + 8, 2, 512,
        eo + (size_t)4 * B * 2, (size_t)B * 2);

    gather_k<<<dim3(B / 256), 256, 0, stream>>>(eo, label, out_sout, B);
}

// Round 2
// 620.907 us; speedup vs baseline: 1.8646x; 1.0788x over previous
//
#include <hip/hip_runtime.h>

typedef unsigned short u16;
typedef short s8v __attribute__((ext_vector_type(8)));
typedef float f4v __attribute__((ext_vector_type(4)));

#define AS1 __attribute__((address_space(1)))
#define AS3 __attribute__((address_space(3)))

__device__ __forceinline__ float bf2f(u16 u) {
    union { unsigned int i; float f; } x; x.i = ((unsigned int)u) << 16; return x.f;
}
__device__ __forceinline__ u16 f2bf(float f) {
    union { float f; unsigned int i; } x; x.f = f;
    unsigned int r = x.i + 0x7fffu + ((x.i >> 16) & 1u);
    return (u16)(r >> 16);
}

// async global->LDS, 16B per lane; LDS dest = wave-uniform base + lane*16
__device__ __forceinline__ void glds16(const u16* g, u16* l) {
    __builtin_amdgcn_global_load_lds((AS1 void*)(g), (AS3 void*)(l), 16, 0, 0);
}

// swizzled LDS element offset for a [row][64] bf16 tile, kq multiple of 8.
// slot chunk = (kq>>3) ^ (row&7); inverse applied on the staging source.
__device__ __forceinline__ int swz(int row, int kq) {
    return row * 64 + ((((kq >> 3) ^ row) & 7) << 3);
}

// ---------------------------------------------------------------------------
// Weight convert+transpose: W f32 [K][N] -> WT bf16 [N][K]. Batched over z;
// z < zSplit reads Wa[z], else Wb[z-zSplit] (merges expert batch + domain).
// ---------------------------------------------------------------------------
__global__ __launch_bounds__(256) void convT2_k(const float* __restrict__ Wa,
        const float* __restrict__ Wb, int zSplit,
        u16* __restrict__ WT, int N, int K)
{
    const int z = blockIdx.z;
    const float* W = (z < zSplit) ? Wa + (size_t)z * K * N
                                  : Wb + (size_t)(z - zSplit) * K * N;
    WT += (size_t)z * K * N;
    const int n0 = blockIdx.x * 64, k0 = blockIdx.y * 64;
    __shared__ float t[64][65];
    const int r = threadIdx.x >> 2;          // 0..63
    const int c = (threadIdx.x & 3) << 4;    // 0,16,32,48
    const float* wp = W + (size_t)(k0 + r) * N + n0 + c;
    #pragma unroll
    for (int q = 0; q < 16; q += 4) {
        float4 f = *(const float4*)(wp + q);
        t[c + q + 0][r] = f.x; t[c + q + 1][r] = f.y;
        t[c + q + 2][r] = f.z; t[c + q + 3][r] = f.w;
    }
    __syncthreads();
    u16* op = WT + (size_t)(n0 + r) * K + k0 + c;
    #pragma unroll
    for (int q = 0; q < 16; q += 8) {
        s8v v;
        #pragma unroll
        for (int j = 0; j < 8; ++j) v[j] = (short)f2bf(t[r][c + q + j]);
        *(s8v*)(op + q) = v;
    }
}

// ---------------------------------------------------------------------------
// Elementwise f32 -> bf16 (8 per thread). n8 = elems/8.
// ---------------------------------------------------------------------------
__global__ __launch_bounds__(256) void conv_k(const float* __restrict__ in,
        u16* __restrict__ out, int n8)
{
    const int i = blockIdx.x * 256 + threadIdx.x;
    if (i >= n8) return;
    const float4 f0 = ((const float4*)in)[i * 2];
    const float4 f1 = ((const float4*)in)[i * 2 + 1];
    s8v v;
    v[0]=(short)f2bf(f0.x); v[1]=(short)f2bf(f0.y);
    v[2]=(short)f2bf(f0.z); v[3]=(short)f2bf(f0.w);
    v[4]=(short)f2bf(f1.x); v[5]=(short)f2bf(f1.y);
    v[6]=(short)f2bf(f1.z); v[7]=(short)f2bf(f1.w);
    ((s8v*)out)[i] = v;
}

// ---------------------------------------------------------------------------
// Batched bf16 GEMM: out[z] = epi(A[z] @ WT[z]^T).
// 128x128 tile, BK=64, 4 waves, 4x4 16x16 frags/wave, global_load_lds(16B),
// T2 XOR-swizzle (pre-swizzled source + swizzled ds_read), double-buffered
// 2-phase prefetch (one barrier per K-step), setprio around MFMA cluster.
// ---------------------------------------------------------------------------
__device__ __forceinline__ void stage_tile(u16* AsH, u16* BsH,
        const u16* ga, const u16* gb, int kk, int ldsq, int K)
{
    #pragma unroll
    for (int q = 0; q < 4; ++q) {
        glds16(ga + kk + (size_t)q * 32 * K, AsH + q * 2048 + ldsq);
        glds16(gb + kk + (size_t)q * 32 * K, BsH + q * 2048 + ldsq);
    }
}

template<int HASDOM>
__global__ __launch_bounds__(256) void gemm_bt128_k(
    const u16* __restrict__ A0, size_t aStrideZ,
    const u16* __restrict__ WT0,
    const float* __restrict__ ebias,                       // [Z][N] expert bias
    const float* __restrict__ dbias, const float* __restrict__ dgam,
    const float* __restrict__ dbet,  const float* __restrict__ dmean,
    const float* __restrict__ dvar,  int zdom,
    u16* __restrict__ out0, int M, int N, int K)
{
    const int z = blockIdx.z;
    const u16* A  = A0  + (size_t)z * aStrideZ;
    const u16* WT = WT0 + (size_t)z * N * K;
    u16* out = out0 + (size_t)z * M * N;

    const int n0 = blockIdx.x * 128, m0 = blockIdx.y * 128;
    const int t = threadIdx.x;
    const int w = t >> 6, lane = t & 63;
    const int lq = lane >> 4, lr = lane & 15;
    const int wm = (w >> 1) * 64, wn = (w & 1) * 64;

    __shared__ __align__(16) u16 As[2 * 128 * 64];
    __shared__ __align__(16) u16 Bs[2 * 128 * 64];

    f4v acc[4][4] = {};

    // staging: thread t covers row (t>>3), 16B chunk (t&7); source chunk is
    // pre-swizzled by row&7 so the linear glds write lands T2-swizzled.
    const int schunk = ((t & 7) ^ ((t >> 3) & 7)) << 3;
    const u16* ga = A  + (size_t)(m0 + (t >> 3)) * K + schunk;
    const u16* gb = WT + (size_t)(n0 + (t >> 3)) * K + schunk;
    const int ldsq = w * 512;   // elements

    const int NT = K >> 6;
    int cur = 0;
    stage_tile(As, Bs, ga, gb, 0, ldsq, K);
    __syncthreads();

    for (int tk = 0; tk < NT; ++tk) {
        if (tk + 1 < NT)
            stage_tile(As + (cur ^ 1) * 8192, Bs + (cur ^ 1) * 8192,
                       ga, gb, (tk + 1) << 6, ldsq, K);
        const u16* Ah = As + cur * 8192;
        const u16* Bh = Bs + cur * 8192;
        __builtin_amdgcn_s_setprio(1);
        #pragma unroll
        for (int ks = 0; ks < 64; ks += 32) {
            const int kq = ks + (lq << 3);
            s8v a[4], b[4];
            #pragma unroll
            for (int i = 0; i < 4; ++i) a[i] = *(const s8v*)&Ah[swz(wm + i*16 + lr, kq)];
            #pragma unroll
            for (int j = 0; j < 4; ++j) b[j] = *(const s8v*)&Bh[swz(wn + j*16 + lr, kq)];
            #pragma unroll
            for (int i = 0; i < 4; ++i)
                #pragma unroll
                for (int j = 0; j < 4; ++j)
                    acc[i][j] = __builtin_amdgcn_mfma_f32_16x16x32_bf16(a[i], b[j], acc[i][j], 0, 0, 0);
        }
        __builtin_amdgcn_s_setprio(0);
        __syncthreads();
        cur ^= 1;
    }

    // epilogue: frag D mapping col=lane&15, row=(lane>>4)*4+r
    float scale[4], shift[4];
    const bool dom = HASDOM && (z == zdom);
    #pragma unroll
    for (int j = 0; j < 4; ++j) {
        const int c = n0 + wn + j * 16 + lr;
        if (dom) {
            const float s = dgam[c] / sqrtf(dvar[c] + 1e-5f);
            scale[j] = s;
            shift[j] = (dbias[c] - dmean[c]) * s + dbet[c];
        } else {
            scale[j] = 1.f;
            shift[j] = ebias[(size_t)z * N + c];
        }
    }
    const int r0 = lq << 2;
    #pragma unroll
    for (int i = 0; i < 4; ++i) {
        #pragma unroll
        for (int r = 0; r < 4; ++r) {
            const int grow = m0 + wm + i * 16 + r0 + r;
            u16* orow = out + (size_t)grow * N + n0 + wn + lr;
            #pragma unroll
            for (int j = 0; j < 4; ++j) {
                float y = fmaf(acc[i][j][r], scale[j], shift[j]);
                if (dom) y = fmaxf(y, 0.f);
                orow[j * 16] = f2bf(y);
            }
        }
    }
}

// ---------------------------------------------------------------------------
// f32-exact split-K GEMM (routing h1 partials, no epilogue).
// Grid (N/64, M/64, 4); slice z covers K range [z*Ks, (z+1)*Ks).
// ---------------------------------------------------------------------------
__global__ __launch_bounds__(256) void gemm_f32sk_k(
    const float* __restrict__ A, const float* __restrict__ W,
    float* __restrict__ out, int M, int N, int K, int Ks)
{
    const int n0 = blockIdx.x * 64, m0 = blockIdx.y * 64;
    const int kb = blockIdx.z * Ks;
    out += (size_t)blockIdx.z * M * N;
    const int tid = threadIdx.x;
    const int tx = tid & 15, ty = tid >> 4;
    __shared__ float As[64][65];
    __shared__ float Bs[64][64];
    float acc[4][4] = {};
    const int sr = tid >> 2;
    const int sc = (tid & 3) << 4;
    for (int kk = kb; kk < kb + Ks; kk += 64) {
        const float* ap = A + (size_t)(m0 + sr) * K + kk + sc;
        #pragma unroll
        for (int q = 0; q < 4; ++q) {
            float4 f = *(const float4*)(ap + q * 4);
            As[sr][sc + q*4 + 0] = f.x; As[sr][sc + q*4 + 1] = f.y;
            As[sr][sc + q*4 + 2] = f.z; As[sr][sc + q*4 + 3] = f.w;
        }
        const float* wp = W + (size_t)(kk + sr) * N + n0 + sc;
        #pragma unroll
        for (int q = 0; q < 4; ++q)
            *(float4*)&Bs[sr][sc + q*4] = *(const float4*)(wp + q * 4);
        __syncthreads();
        #pragma unroll 4
        for (int kq = 0; kq < 64; ++kq) {
            float a[4], bv[4];
            #pragma unroll
            for (int i = 0; i < 4; ++i) a[i] = As[ty*4 + i][kq];
            #pragma unroll
            for (int j = 0; j < 4; ++j) bv[j] = Bs[kq][tx*4 + j];
            #pragma unroll
            for (int i = 0; i < 4; ++i)
                #pragma unroll
                for (int j = 0; j < 4; ++j)
                    acc[i][j] = fmaf(a[i], bv[j], acc[i][j]);
        }
        __syncthreads();
    }
    #pragma unroll
    for (int j = 0; j < 4; ++j) {
        const int c = n0 + tx*4 + j;
        #pragma unroll
        for (int i = 0; i < 4; ++i)
            out[(size_t)(m0 + ty*4 + i) * N + c] = acc[i][j];
    }
}

// ---------------------------------------------------------------------------
// Fused routing tail: combine 4 K-partials + BN1 + ReLU -> h2 GEMM + BN2 +
// ReLU -> classifier + log_softmax + argmax. 4 samples/block.
// ---------------------------------------------------------------------------
__global__ __launch_bounds__(256) void h2cls_k(
    const float* __restrict__ hp,   // [4][B][512] raw partial sums
    const float* __restrict__ bb1, const float* __restrict__ bg1,
    const float* __restrict__ bbe1, const float* __restrict__ bm1,
    const float* __restrict__ bv1,
    const float* __restrict__ bw2, const float* __restrict__ bb2,
    const float* __restrict__ bg2, const float* __restrict__ bbe2,
    const float* __restrict__ bm2, const float* __restrict__ bv2,
    const float* __restrict__ cw,  const float* __restrict__ cb,
    float* __restrict__ out_src, int* __restrict__ label, int B)
{
    const int b0 = blockIdx.x * 4;
    const int t = threadIdx.x;
    const size_t sl = (size_t)B * 512;
    __shared__ float h1s[4][512];
    __shared__ float h2s[4][256];

    #pragma unroll
    for (int cc = 0; cc < 2; ++cc) {
        const int c = t + cc * 256;
        const float sc = bg1[c] / sqrtf(bv1[c] + 1e-5f);
        const float sh = (bb1[c] - bm1[c]) * sc + bbe1[c];
        #pragma unroll
        for (int s = 0; s < 4; ++s) {
            const size_t ix = (size_t)(b0 + s) * 512 + c;
            const float v = hp[ix] + hp[ix + sl] + hp[ix + 2*sl] + hp[ix + 3*sl];
            h1s[s][c] = fmaxf(fmaf(v, sc, sh), 0.f);
        }
    }
    __syncthreads();

    float acc[4] = {};
    #pragma unroll 4
    for (int k = 0; k < 512; ++k) {
        const float wv = bw2[(size_t)k * 256 + t];
        #pragma unroll
        for (int s = 0; s < 4; ++s) acc[s] = fmaf(h1s[s][k], wv, acc[s]);
    }
    const float sc2 = bg2[t] / sqrtf(bv2[t] + 1e-5f);
    const float sh2 = (bb2[t] - bm2[t]) * sc2 + bbe2[t];
    #pragma unroll
    for (int s = 0; s < 4; ++s) h2s[s][t] = fmaxf(fmaf(acc[s], sc2, sh2), 0.f);
    __syncthreads();

    const int s = t >> 6, lane = t & 63;
    float p[8] = {};
    for (int k = lane; k < 256; k += 64) {
        const float x = h2s[s][k];
        #pragma unroll
        for (int c = 0; c < 8; ++c) p[c] = fmaf(x, cw[k * 8 + c], p[c]);
    }
    #pragma unroll
    for (int off = 32; off; off >>= 1)
        #pragma unroll
        for (int c = 0; c < 8; ++c) p[c] += __shfl_xor(p[c], off, 64);
    if (lane == 0) {
        const int b = b0 + s;
        float lg[8];
        #pragma unroll
        for (int c = 0; c < 8; ++c) lg[c] = p[c] + cb[c];
        float mx = lg[0]; int am = 0;
        #pragma unroll
        for (int c = 1; c < 8; ++c) if (lg[c] > mx) { mx = lg[c]; am = c; }
        float ssum = 0.f;
        #pragma unroll
        for (int c = 0; c < 8; ++c) ssum += expf(lg[c] - mx);
        const float lse = mx + logf(ssum);
        #pragma unroll
        for (int c = 0; c < 8; ++c) out_src[b * 8 + c] = lg[c] - lse;
        label[b] = am;
    }
}

// ---------------------------------------------------------------------------
// In-place LayerNorm + ReLU, batched over z (grid.y), N in {512,1024}.
// ---------------------------------------------------------------------------
template<int N>
__global__ __launch_bounds__(256) void ln_relu_k(u16* __restrict__ Y,
        const float* __restrict__ g, const float* __restrict__ bb)
{
    const int z = blockIdx.y;
    u16* y = Y + ((size_t)z * gridDim.x + blockIdx.x) * N;
    const float* gz = g  + (size_t)z * N;
    const float* bz = bb + (size_t)z * N;
    const int t = threadIdx.x;
    constexpr int C = N >> 8;   // 4 or 2
    float vals[C];
    if (C == 4) {
        ushort4 u = ((const ushort4*)y)[t];
        vals[0] = bf2f(u.x); vals[1] = bf2f(u.y);
        vals[2] = bf2f(u.z); vals[3] = bf2f(u.w);
    } else {
        ushort2 u = ((const ushort2*)y)[t];
        vals[0] = bf2f(u.x); vals[1] = bf2f(u.y);
    }
    float s = 0.f, sq = 0.f;
    #pragma unroll
    for (int i = 0; i < C; ++i) { s += vals[i]; sq += vals[i] * vals[i]; }
    #pragma unroll
    for (int off = 32; off; off >>= 1) {
        s  += __shfl_xor(s,  off, 64);
        sq += __shfl_xor(sq, off, 64);
    }
    __shared__ float rs[4], rq[4];
    if ((t & 63) == 0) { rs[t >> 6] = s; rq[t >> 6] = sq; }
    __syncthreads();
    s  = rs[0] + rs[1] + rs[2] + rs[3];
    sq = rq[0] + rq[1] + rq[2] + rq[3];
    const float inv = 1.f / (float)N;
    const float mu  = s * inv;
    const float var = sq * inv - mu * mu;
    const float rstd = rsqrtf(var + 1e-5f);
    if (C == 4) {
        float4 gv = ((const float4*)gz)[t];
        float4 bv = ((const float4*)bz)[t];
        ushort4 o;
        o.x = f2bf(fmaxf((vals[0] - mu) * rstd * gv.x + bv.x, 0.f));
        o.y = f2bf(fmaxf((vals[1] - mu) * rstd * gv.y + bv.y, 0.f));
        o.z = f2bf(fmaxf((vals[2] - mu) * rstd * gv.z + bv.z, 0.f));
        o.w = f2bf(fmaxf((vals[3] - mu) * rstd * gv.w + bv.w, 0.f));
        ((ushort4*)y)[t] = o;
    } else {
        float2 gv = ((const float2*)gz)[t];
        float2 bv = ((const float2*)bz)[t];
        ushort2 o;
        o.x = f2bf(fmaxf((vals[0] - mu) * rstd * gv.x + bv.x, 0.f));
        o.y = f2bf(fmaxf((vals[1] - mu) * rstd * gv.y + bv.y, 0.f));
        ((ushort2*)y)[t] = o;
    }
}

// ---------------------------------------------------------------------------
// 2-class head + log_softmax, batched over z (grid.y). 1 wave/row.
// ---------------------------------------------------------------------------
__global__ __launch_bounds__(64) void head2_k(const u16* __restrict__ X, size_t xsz,
        const float* __restrict__ W, size_t wsz,
        const float* __restrict__ bias, size_t bsz,
        int K, float* __restrict__ out, size_t osz)
{
    const int b = blockIdx.x, z = blockIdx.y;
    const int lane = threadIdx.x;
    const u16* x = X + z * xsz + (size_t)b * K;
    const float* Wz = W + z * wsz;
    const float* bz = bias + z * bsz;
    float* o = out + z * osz + (size_t)b * 2;
    float p0 = 0.f, p1 = 0.f;
    for (int k = lane; k < K; k += 64) {
        const float xv = bf2f(x[k]);
        p0 = fmaf(xv, Wz[k * 2],     p0);
        p1 = fmaf(xv, Wz[k * 2 + 1], p1);
    }
    #pragma unroll
    for (int off = 32; off; off >>= 1) {
        p0 += __shfl_xor(p0, off, 64);
        p1 += __shfl_xor(p1, off, 64);
    }
    if (lane == 0) {
        const float l0 = p0 + bz[0];
        const float l1 = p1 + bz[1];
        const float mx = fmaxf(l0, l1);
        const float lse = mx + logf(expf(l0 - mx) + expf(l1 - mx));
        o[0] = l0 - lse;
        o[1] = l1 - lse;
    }
}

__global__ __launch_bounds__(256) void gather_k(const float* __restrict__ eo,
        const int* __restrict__ label, float* __restrict__ out, int B)
{
    const int b = blockIdx.x * 256 + threadIdx.x;
    if (b >= B) return;
    const int e = label[b];
    out[b * 2]     = eo[((size_t)e * B + b) * 2];
    out[b * 2 + 1] = eo[((size_t)e * B + b) * 2 + 1];
}

__global__ __launch_bounds__(256) void copy16_k(const uint4* __restrict__ in,
                                                uint4* __restrict__ out, int n16)
{
    const int i = blockIdx.x * blockDim.x + threadIdx.x;
    if (i < n16) out[i] = in[i];
}

// ---------------------------------------------------------------------------

extern "C" void kernel_launch(void* const* d_in, const int* in_sizes, int n_in,
                              void* d_out, int out_size, void* d_ws, size_t ws_size,
                              hipStream_t stream)
{
    const int B = 2048, D = 1280, E = 8;

    const float* src = (const float*)d_in[0];
    const float *bw1 = (const float*)d_in[1],  *bb1 = (const float*)d_in[2],
                *bg1 = (const float*)d_in[3],  *bbe1 = (const float*)d_in[4],
                *bm1 = (const float*)d_in[5],  *bv1 = (const float*)d_in[6];
    const float *bw2 = (const float*)d_in[7],  *bb2 = (const float*)d_in[8],
                *bg2 = (const float*)d_in[9],  *bbe2 = (const float*)d_in[10],
                *bm2 = (const float*)d_in[11], *bv2 = (const float*)d_in[12];
    const float *cw  = (const float*)d_in[13], *cb  = (const float*)d_in[14];
    const float *dw1 = (const float*)d_in[15], *db1 = (const float*)d_in[16],
                *dg1 = (const float*)d_in[17], *dbe1 = (const float*)d_in[18],
                *dm1 = (const float*)d_in[19], *dv1 = (const float*)d_in[20];
    const float *dw2 = (const float*)d_in[21], *db2 = (const float*)d_in[22],
                *dg2 = (const float*)d_in[23], *dbe2 = (const float*)d_in[24],
                *dm2 = (const float*)d_in[25], *dv2 = (const float*)d_in[26];
    const float *dw3 = (const float*)d_in[27], *db3 = (const float*)d_in[28],
                *dg3 = (const float*)d_in[29], *dbe3 = (const float*)d_in[30],
                *dm3 = (const float*)d_in[31], *dv3 = (const float*)d_in[32];
    const float *dw4 = (const float*)d_in[33], *db4 = (const float*)d_in[34];
    const float *ew1 = (const float*)d_in[35], *eb1 = (const float*)d_in[36],
                *eg1 = (const float*)d_in[37], *ebe1 = (const float*)d_in[38];
    const float *ew2 = (const float*)d_in[39], *eb2 = (const float*)d_in[40],
                *eg2 = (const float*)d_in[41], *ebe2 = (const float*)d_in[42];
    const float *ew3 = (const float*)d_in[43], *eb3 = (const float*)d_in[44],
                *eg3 = (const float*)d_in[45], *ebe3 = (const float*)d_in[46];
    const float *ew4 = (const float*)d_in[47], *eb4 = (const float*)d_in[48];

    float* out_src   = (float*)d_out;
    float* out_dclf  = out_src + B * E;
    float* out_sout  = out_dclf + B * 2;
    float* out_share = out_sout + B * 2;

    // ws layout (peak 60.44 MB):
    //   wslot [0, 13.11M)       bf16, JIT-transposed weights, up to 5 x 1024x1280
    //   srcb  [13.11M, 18.35M)  bf16 [2048][1280]
    //   acta  [18.35M, 39.32M)  bf16 5 x [2048][1024]   (hp f32 [4][2048][512] overlaps)
    //   actb  [39.32M, 60.29M)  bf16 5 x [2048][1024]
    //   eo    [60.29M, +128K) ; label [+8K)
    char* ws = (char*)d_ws;
    u16*   wslot = (u16*)ws;
    u16*   srcb  = (u16*)(ws + 13107200);
    u16*   acta  = (u16*)(ws + 18350080);
    u16*   actb  = (u16*)(ws + 39321600);
    float* eo    = (float*)(ws + 60293120);
    int*   label = (int*)(ws + 60424192);
    float* hp    = (float*)(ws + 18350080);   // overlaps acta; dead before experts

    const size_t s1024 = (size_t)B * 1024, s512 = (size_t)B * 512;

    // ---- src conversion + share passthrough ----
    conv_k<<<dim3(B * D / 8 / 256), 256, 0, stream>>>(src, srcb, B * D / 8);
    copy16_k<<<dim3(B * D * 4 / 16 / 256), 256, 0, stream>>>(
        (const uint4*)src, (uint4*)out_share, B * D * 4 / 16);

    // ---- routing: split-K=4 f32 GEMM -> fused combine/BN/h2/classifier ----
    gemm_f32sk_k<<<dim3(512 / 64, B / 64, 4), 256, 0, stream>>>(
        src, bw1, hp, B, 512, D, 320);
    h2cls_k<<<dim3(B / 4), 256, 0, stream>>>(
        hp, bb1, bg1, bbe1, bm1, bv1, bw2, bb2, bg2, bbe2, bm2, bv2,
        cw, cb, out_src, label, B);

    // ---- group A: experts 0..3 + domain classifier as z=4 ----
    convT2_k<<<dim3(16, 20, 5), 256, 0, stream>>>(ew1, dw1, 4, wslot, 1024, 1280);
    gemm_bt128_k<1><<<dim3(8, 16, 5), 256, 0, stream>>>(
        srcb, 0, wslot, eb1, db1, dg1, dbe1, dm1, dv1, 4, acta, B, 1024, 1280);
    ln_relu_k<1024><<<dim3(B, 4), 256, 0, stream>>>(acta, eg1, ebe1);

    convT2_k<<<dim3(16, 16, 5), 256, 0, stream>>>(ew2, dw2, 4, wslot, 1024, 1024);
    gemm_bt128_k<1><<<dim3(8, 16, 5), 256, 0, stream>>>(
        acta, s1024, wslot, eb2, db2, dg2, dbe2, dm2, dv2, 4, actb, B, 1024, 1024);
    ln_relu_k<1024><<<dim3(B, 4), 256, 0, stream>>>(actb, eg2, ebe2);

    convT2_k<<<dim3(8, 16, 5), 256, 0, stream>>>(ew3, dw3, 4, wslot, 512, 1024);
    gemm_bt128_k<1><<<dim3(4, 16, 5), 256, 0, stream>>>(
        actb, s1024, wslot, eb3, db3, dg3, dbe3, dm3, dv3, 4, acta, B, 512, 1024);
    ln_relu_k<512><<<dim3(B, 4), 256, 0, stream>>>(acta, eg3, ebe3);

    head2_k<<<dim3(B, 4), 64, 0, stream>>>(
        acta, s512, ew4, 1024, eb4, 2, 512, eo, (size_t)B * 2);
    head2_k<<<dim3(B, 1), 64, 0, stream>>>(
        acta + (size_t)4 * B * 512, 0, dw4, 0, db4, 0, 512, out_dclf, 0);

    // ---- group B: experts 4..7 ----
    convT2_k<<<dim3(16, 20, 4), 256, 0, stream>>>(
        ew1 + (size_t)4*1280*1024, ew1 + (size_t)4*1280*1024, 4, wslot, 1024, 1280);
    gemm_bt128_k<0><<<dim3(8, 16, 4), 256, 0, stream>>>(
        srcb, 0, wslot, eb1 + (size_t)4*1024,
        nullptr, nullptr, nullptr, nullptr, nullptr, -1, acta, B, 1024, 1280);
    ln_relu_k<1024><<<dim3(B, 4), 256, 0, stream>>>(acta, eg1 + (size_t)4*1024, ebe1 + (size_t)4*1024);

    convT2_k<<<dim3(16, 16, 4), 256, 0, stream>>>(
        ew2 + (size_t)4*1024*1024, ew2 + (size_t)4*1024*1024, 4, wslot, 1024, 1024);
    gemm_bt128_k<0><<<dim3(8, 16, 4), 256, 0, stream>>>(
        acta, s1024, wslot, eb2 + (size_t)4*1024,
        nullptr, nullptr, nullptr, nullptr, nullptr, -1, actb, B, 1024, 1024);
    ln_relu_k<1024><<<dim3(B, 4), 256, 0, stream>>>(actb, eg2 + (size_t)4*1024, ebe2 + (size_t)4*1024);

    convT2_k<<<dim3(8, 16, 4), 256, 0, stream>>>(
        ew3 + (size_t)4*1024*512, ew3 + (size_t)4*1024*512, 4, wslot, 512, 1024);
    gemm_bt128_k<0><<<dim3(4, 16, 4), 256, 0, stream>>>(
        actb, s1024, wslot, eb3 + (size_t)4*512,
        nullptr, nullptr, nullptr, nullptr, nullptr, -1, acta, B, 512, 1024);
    ln_relu_k<512><<<dim3(B, 4), 256, 0, stream>>>(acta, eg3 + (size_t)4*512, ebe3 + (size_t)4*512);

    head2_k<<<dim3(B, 4), 64, 0, stream>>>(
        acta, s512, ew4 + (size_t)4*512*2, 1024, eb4 + 8, 2, 512,
        eo + (size_t)4 * B * 2, (size_t)B * 2);

    gather_k<<<dim3(B / 256), 256, 0, stream>>>(eo, label, out_sout, B);
}

// Round 3
// 582.798 us; speedup vs baseline: 1.9865x; 1.0654x over previous
//
#include <hip/hip_runtime.h>

typedef unsigned short u16;
typedef short s8v __attribute__((ext_vector_type(8)));
typedef float f4v __attribute__((ext_vector_type(4)));

#define AS1 __attribute__((address_space(1)))
#define AS3 __attribute__((address_space(3)))

__device__ __forceinline__ float bf2f(u16 u) {
    union { unsigned int i; float f; } x; x.i = ((unsigned int)u) << 16; return x.f;
}
__device__ __forceinline__ u16 f2bf(float f) {
    union { float f; unsigned int i; } x; x.f = f;
    unsigned int r = x.i + 0x7fffu + ((x.i >> 16) & 1u);
    return (u16)(r >> 16);
}

// async global->LDS, 16B per lane; LDS dest = wave-uniform base + lane*16
__device__ __forceinline__ void glds16(const u16* g, u16* l) {
    __builtin_amdgcn_global_load_lds((AS1 void*)(g), (AS3 void*)(l), 16, 0, 0);
}

// swizzled LDS element offset for a [row][64] bf16 tile, kq multiple of 8.
__device__ __forceinline__ int swz(int row, int kq) {
    return row * 64 + ((((kq >> 3) ^ row) & 7) << 3);
}

// ---------------------------------------------------------------------------
// Weight convert+transpose: W f32 [K][N] -> WT bf16 [N][K]. Batched over z;
// z < zSplit reads Wa[z], else Wb[z-zSplit].
// ---------------------------------------------------------------------------
__global__ __launch_bounds__(256) void convT2_k(const float* __restrict__ Wa,
        const float* __restrict__ Wb, int zSplit,
        u16* __restrict__ WT, int N, int K)
{
    const int z = blockIdx.z;
    const float* W = (z < zSplit) ? Wa + (size_t)z * K * N
                                  : Wb + (size_t)(z - zSplit) * K * N;
    WT += (size_t)z * K * N;
    const int n0 = blockIdx.x * 64, k0 = blockIdx.y * 64;
    __shared__ float t[64][65];
    const int r = threadIdx.x >> 2;          // 0..63
    const int c = (threadIdx.x & 3) << 4;    // 0,16,32,48
    const float* wp = W + (size_t)(k0 + r) * N + n0 + c;
    #pragma unroll
    for (int q = 0; q < 16; q += 4) {
        float4 f = *(const float4*)(wp + q);
        t[c + q + 0][r] = f.x; t[c + q + 1][r] = f.y;
        t[c + q + 2][r] = f.z; t[c + q + 3][r] = f.w;
    }
    __syncthreads();
    u16* op = WT + (size_t)(n0 + r) * K + k0 + c;
    #pragma unroll
    for (int q = 0; q < 16; q += 8) {
        s8v v;
        #pragma unroll
        for (int j = 0; j < 8; ++j) v[j] = (short)f2bf(t[r][c + q + j]);
        *(s8v*)(op + q) = v;
    }
}

// ---------------------------------------------------------------------------
// Elementwise f32 -> bf16 (8 per thread). n8 = elems/8.
// ---------------------------------------------------------------------------
__global__ __launch_bounds__(256) void conv_k(const float* __restrict__ in,
        u16* __restrict__ out, int n8)
{
    const int i = blockIdx.x * 256 + threadIdx.x;
    if (i >= n8) return;
    const float4 f0 = ((const float4*)in)[i * 2];
    const float4 f1 = ((const float4*)in)[i * 2 + 1];
    s8v v;
    v[0]=(short)f2bf(f0.x); v[1]=(short)f2bf(f0.y);
    v[2]=(short)f2bf(f0.z); v[3]=(short)f2bf(f0.w);
    v[4]=(short)f2bf(f1.x); v[5]=(short)f2bf(f1.y);
    v[6]=(short)f2bf(f1.z); v[7]=(short)f2bf(f1.w);
    ((s8v*)out)[i] = v;
}

// ---------------------------------------------------------------------------
// Batched bf16 GEMM, 128x128 tile, dbuf 2-phase, T2 swizzle, setprio.
// ---------------------------------------------------------------------------
__device__ __forceinline__ void stage_tile(u16* AsH, u16* BsH,
        const u16* ga, const u16* gb, int kk, int ldsq, int K)
{
    #pragma unroll
    for (int q = 0; q < 4; ++q) {
        glds16(ga + kk + (size_t)q * 32 * K, AsH + q * 2048 + ldsq);
        glds16(gb + kk + (size_t)q * 32 * K, BsH + q * 2048 + ldsq);
    }
}

template<int HASDOM>
__global__ __launch_bounds__(256) void gemm_bt128_k(
    const u16* __restrict__ A0, size_t aStrideZ,
    const u16* __restrict__ WT0,
    const float* __restrict__ ebias,
    const float* __restrict__ dbias, const float* __restrict__ dgam,
    const float* __restrict__ dbet,  const float* __restrict__ dmean,
    const float* __restrict__ dvar,  int zdom,
    u16* __restrict__ out0, int M, int N, int K)
{
    const int z = blockIdx.z;
    const u16* A  = A0  + (size_t)z * aStrideZ;
    const u16* WT = WT0 + (size_t)z * N * K;
    u16* out = out0 + (size_t)z * M * N;

    const int n0 = blockIdx.x * 128, m0 = blockIdx.y * 128;
    const int t = threadIdx.x;
    const int w = t >> 6, lane = t & 63;
    const int lq = lane >> 4, lr = lane & 15;
    const int wm = (w >> 1) * 64, wn = (w & 1) * 64;

    __shared__ __align__(16) u16 As[2 * 128 * 64];
    __shared__ __align__(16) u16 Bs[2 * 128 * 64];

    f4v acc[4][4] = {};

    const int schunk = ((t & 7) ^ ((t >> 3) & 7)) << 3;
    const u16* ga = A  + (size_t)(m0 + (t >> 3)) * K + schunk;
    const u16* gb = WT + (size_t)(n0 + (t >> 3)) * K + schunk;
    const int ldsq = w * 512;   // elements

    const int NT = K >> 6;
    int cur = 0;
    stage_tile(As, Bs, ga, gb, 0, ldsq, K);
    __syncthreads();

    for (int tk = 0; tk < NT; ++tk) {
        if (tk + 1 < NT)
            stage_tile(As + (cur ^ 1) * 8192, Bs + (cur ^ 1) * 8192,
                       ga, gb, (tk + 1) << 6, ldsq, K);
        const u16* Ah = As + cur * 8192;
        const u16* Bh = Bs + cur * 8192;
        __builtin_amdgcn_s_setprio(1);
        #pragma unroll
        for (int ks = 0; ks < 64; ks += 32) {
            const int kq = ks + (lq << 3);
            s8v a[4], b[4];
            #pragma unroll
            for (int i = 0; i < 4; ++i) a[i] = *(const s8v*)&Ah[swz(wm + i*16 + lr, kq)];
            #pragma unroll
            for (int j = 0; j < 4; ++j) b[j] = *(const s8v*)&Bh[swz(wn + j*16 + lr, kq)];
            #pragma unroll
            for (int i = 0; i < 4; ++i)
                #pragma unroll
                for (int j = 0; j < 4; ++j)
                    acc[i][j] = __builtin_amdgcn_mfma_f32_16x16x32_bf16(a[i], b[j], acc[i][j], 0, 0, 0);
        }
        __builtin_amdgcn_s_setprio(0);
        __syncthreads();
        cur ^= 1;
    }

    float scale[4], shift[4];
    const bool dom = HASDOM && (z == zdom);
    #pragma unroll
    for (int j = 0; j < 4; ++j) {
        const int c = n0 + wn + j * 16 + lr;
        if (dom) {
            const float s = dgam[c] / sqrtf(dvar[c] + 1e-5f);
            scale[j] = s;
            shift[j] = (dbias[c] - dmean[c]) * s + dbet[c];
        } else {
            scale[j] = 1.f;
            shift[j] = ebias[(size_t)z * N + c];
        }
    }
    const int r0 = lq << 2;
    #pragma unroll
    for (int i = 0; i < 4; ++i) {
        #pragma unroll
        for (int r = 0; r < 4; ++r) {
            const int grow = m0 + wm + i * 16 + r0 + r;
            u16* orow = out + (size_t)grow * N + n0 + wn + lr;
            #pragma unroll
            for (int j = 0; j < 4; ++j) {
                float y = fmaf(acc[i][j][r], scale[j], shift[j]);
                if (dom) y = fmaxf(y, 0.f);
                orow[j * 16] = f2bf(y);
            }
        }
    }
}

// ---------------------------------------------------------------------------
// f32-exact split-K GEMM (routing h1 partials, no epilogue).
// ---------------------------------------------------------------------------
__global__ __launch_bounds__(256) void gemm_f32sk_k(
    const float* __restrict__ A, const float* __restrict__ W,
    float* __restrict__ out, int M, int N, int K, int Ks)
{
    const int n0 = blockIdx.x * 64, m0 = blockIdx.y * 64;
    const int kb = blockIdx.z * Ks;
    out += (size_t)blockIdx.z * M * N;
    const int tid = threadIdx.x;
    const int tx = tid & 15, ty = tid >> 4;
    __shared__ float As[64][65];
    __shared__ float Bs[64][64];
    float acc[4][4] = {};
    const int sr = tid >> 2;
    const int sc = (tid & 3) << 4;
    for (int kk = kb; kk < kb + Ks; kk += 64) {
        const float* ap = A + (size_t)(m0 + sr) * K + kk + sc;
        #pragma unroll
        for (int q = 0; q < 4; ++q) {
            float4 f = *(const float4*)(ap + q * 4);
            As[sr][sc + q*4 + 0] = f.x; As[sr][sc + q*4 + 1] = f.y;
            As[sr][sc + q*4 + 2] = f.z; As[sr][sc + q*4 + 3] = f.w;
        }
        const float* wp = W + (size_t)(kk + sr) * N + n0 + sc;
        #pragma unroll
        for (int q = 0; q < 4; ++q)
            *(float4*)&Bs[sr][sc + q*4] = *(const float4*)(wp + q * 4);
        __syncthreads();
        #pragma unroll 4
        for (int kq = 0; kq < 64; ++kq) {
            float a[4], bv[4];
            #pragma unroll
            for (int i = 0; i < 4; ++i) a[i] = As[ty*4 + i][kq];
            #pragma unroll
            for (int j = 0; j < 4; ++j) bv[j] = Bs[kq][tx*4 + j];
            #pragma unroll
            for (int i = 0; i < 4; ++i)
                #pragma unroll
                for (int j = 0; j < 4; ++j)
                    acc[i][j] = fmaf(a[i], bv[j], acc[i][j]);
        }
        __syncthreads();
    }
    #pragma unroll
    for (int j = 0; j < 4; ++j) {
        const int c = n0 + tx*4 + j;
        #pragma unroll
        for (int i = 0; i < 4; ++i)
            out[(size_t)(m0 + ty*4 + i) * N + c] = acc[i][j];
    }
}

// ---------------------------------------------------------------------------
// BN scale/shift precompute: scs[k]=g/sqrt(v+eps), shs[k]=(bb-m)*scs+be.
// ---------------------------------------------------------------------------
__global__ __launch_bounds__(256) void bnpre_k(const float* __restrict__ g,
        const float* __restrict__ be, const float* __restrict__ bb,
        const float* __restrict__ m, const float* __restrict__ v,
        float* __restrict__ scs, float* __restrict__ shs, int N)
{
    const int k = blockIdx.x * 256 + threadIdx.x;
    if (k >= N) return;
    const float sc = g[k] / sqrtf(v[k] + 1e-5f);
    scs[k] = sc;
    shs[k] = (bb[k] - m[k]) * sc + be[k];
}

// ---------------------------------------------------------------------------
// Routing h2 GEMM, split-K=4: A = BN1+ReLU(combine4(hp)) on the fly,
// B = bw2 [512][256]. out = raw partials [4][B][256]. Grid (4, B/64, 4).
// ---------------------------------------------------------------------------
__global__ __launch_bounds__(256) void h2gemm_k(
    const float* __restrict__ hp, const float* __restrict__ scs,
    const float* __restrict__ shs, const float* __restrict__ bw2,
    float* __restrict__ out, int B)
{
    const int n0 = blockIdx.x * 64, m0 = blockIdx.y * 64;
    const int kb = blockIdx.z * 128;
    out += (size_t)blockIdx.z * B * 256;
    const size_t sl = (size_t)B * 512;
    const int tid = threadIdx.x;
    const int tx = tid & 15, ty = tid >> 4;
    __shared__ float As[64][65];
    __shared__ float Bs[64][64];
    float acc[4][4] = {};
    const int sr = tid >> 2;
    const int sc = (tid & 3) << 4;
    for (int kk = kb; kk < kb + 128; kk += 64) {
        const float* ap = hp + (size_t)(m0 + sr) * 512 + kk + sc;
        #pragma unroll
        for (int q = 0; q < 4; ++q) {
            const float4 f0 = *(const float4*)(ap + q * 4);
            const float4 f1 = *(const float4*)(ap + sl + q * 4);
            const float4 f2 = *(const float4*)(ap + 2 * sl + q * 4);
            const float4 f3 = *(const float4*)(ap + 3 * sl + q * 4);
            const float4 g = *(const float4*)(scs + kk + sc + q * 4);
            const float4 h = *(const float4*)(shs + kk + sc + q * 4);
            As[sr][sc + q*4 + 0] = fmaxf(fmaf(f0.x + f1.x + f2.x + f3.x, g.x, h.x), 0.f);
            As[sr][sc + q*4 + 1] = fmaxf(fmaf(f0.y + f1.y + f2.y + f3.y, g.y, h.y), 0.f);
            As[sr][sc + q*4 + 2] = fmaxf(fmaf(f0.z + f1.z + f2.z + f3.z, g.z, h.z), 0.f);
            As[sr][sc + q*4 + 3] = fmaxf(fmaf(f0.w + f1.w + f2.w + f3.w, g.w, h.w), 0.f);
        }
        const float* wp = bw2 + (size_t)(kk + sr) * 256 + n0 + sc;
        #pragma unroll
        for (int q = 0; q < 4; ++q)
            *(float4*)&Bs[sr][sc + q*4] = *(const float4*)(wp + q * 4);
        __syncthreads();
        #pragma unroll 4
        for (int kq = 0; kq < 64; ++kq) {
            float a[4], bv[4];
            #pragma unroll
            for (int i = 0; i < 4; ++i) a[i] = As[ty*4 + i][kq];
            #pragma unroll
            for (int j = 0; j < 4; ++j) bv[j] = Bs[kq][tx*4 + j];
            #pragma unroll
            for (int i = 0; i < 4; ++i)
                #pragma unroll
                for (int j = 0; j < 4; ++j)
                    acc[i][j] = fmaf(a[i], bv[j], acc[i][j]);
        }
        __syncthreads();
    }
    #pragma unroll
    for (int j = 0; j < 4; ++j) {
        const int c = n0 + tx*4 + j;
        #pragma unroll
        for (int i = 0; i < 4; ++i)
            out[(size_t)(m0 + ty*4 + i) * 256 + c] = acc[i][j];
    }
}

// ---------------------------------------------------------------------------
// Routing classifier tail: combine 4 h2 partials + BN2 + ReLU + 256->8
// matvec + log_softmax + argmax. One wave per sample, 4 samples/block.
// ---------------------------------------------------------------------------
__global__ __launch_bounds__(256) void cls_k(
    const float* __restrict__ h2p,
    const float* __restrict__ bg2, const float* __restrict__ bbe2,
    const float* __restrict__ bb2, const float* __restrict__ bm2,
    const float* __restrict__ bv2,
    const float* __restrict__ cw,  const float* __restrict__ cb,
    float* __restrict__ out_src, int* __restrict__ label, int B)
{
    const int b = blockIdx.x * 4 + (threadIdx.x >> 6);
    const int lane = threadIdx.x & 63;
    const size_t sl = (size_t)B * 256;
    const float* hb = h2p + (size_t)b * 256 + lane * 4;
    const float4 v0 = *(const float4*)(hb);
    const float4 v1 = *(const float4*)(hb + sl);
    const float4 v2 = *(const float4*)(hb + 2 * sl);
    const float4 v3 = *(const float4*)(hb + 3 * sl);
    const float4 gv = ((const float4*)bg2)[lane];
    const float4 vv = ((const float4*)bv2)[lane];
    const float4 bbv = ((const float4*)bb2)[lane];
    const float4 bmv = ((const float4*)bm2)[lane];
    const float4 bev = ((const float4*)bbe2)[lane];
    float h[4];
    {
        const float s0 = gv.x / sqrtf(vv.x + 1e-5f);
        const float s1 = gv.y / sqrtf(vv.y + 1e-5f);
        const float s2 = gv.z / sqrtf(vv.z + 1e-5f);
        const float s3 = gv.w / sqrtf(vv.w + 1e-5f);
        h[0] = fmaxf(fmaf(v0.x + v1.x + v2.x + v3.x, s0, (bbv.x - bmv.x) * s0 + bev.x), 0.f);
        h[1] = fmaxf(fmaf(v0.y + v1.y + v2.y + v3.y, s1, (bbv.y - bmv.y) * s1 + bev.y), 0.f);
        h[2] = fmaxf(fmaf(v0.z + v1.z + v2.z + v3.z, s2, (bbv.z - bmv.z) * s2 + bev.z), 0.f);
        h[3] = fmaxf(fmaf(v0.w + v1.w + v2.w + v3.w, s3, (bbv.w - bmv.w) * s3 + bev.w), 0.f);
    }
    float p[8] = {};
    #pragma unroll
    for (int j = 0; j < 4; ++j) {
        const float4 c0 = ((const float4*)cw)[(lane * 4 + j) * 2];
        const float4 c1 = ((const float4*)cw)[(lane * 4 + j) * 2 + 1];
        p[0] = fmaf(h[j], c0.x, p[0]); p[1] = fmaf(h[j], c0.y, p[1]);
        p[2] = fmaf(h[j], c0.z, p[2]); p[3] = fmaf(h[j], c0.w, p[3]);
        p[4] = fmaf(h[j], c1.x, p[4]); p[5] = fmaf(h[j], c1.y, p[5]);
        p[6] = fmaf(h[j], c1.z, p[6]); p[7] = fmaf(h[j], c1.w, p[7]);
    }
    #pragma unroll
    for (int off = 32; off; off >>= 1)
        #pragma unroll
        for (int c = 0; c < 8; ++c) p[c] += __shfl_xor(p[c], off, 64);
    if (lane == 0) {
        float lg[8];
        #pragma unroll
        for (int c = 0; c < 8; ++c) lg[c] = p[c] + cb[c];
        float mx = lg[0]; int am = 0;
        #pragma unroll
        for (int c = 1; c < 8; ++c) if (lg[c] > mx) { mx = lg[c]; am = c; }
        float ssum = 0.f;
        #pragma unroll
        for (int c = 0; c < 8; ++c) ssum += expf(lg[c] - mx);
        const float lse = mx + logf(ssum);
        #pragma unroll
        for (int c = 0; c < 8; ++c) out_src[b * 8 + c] = lg[c] - lse;
        label[b] = am;
    }
}

// ---------------------------------------------------------------------------
// In-place LayerNorm + ReLU, batched over z (grid.y), N in {512,1024}.
// ---------------------------------------------------------------------------
template<int N>
__global__ __launch_bounds__(256) void ln_relu_k(u16* __restrict__ Y,
        const float* __restrict__ g, const float* __restrict__ bb)
{
    const int z = blockIdx.y;
    u16* y = Y + ((size_t)z * gridDim.x + blockIdx.x) * N;
    const float* gz = g  + (size_t)z * N;
    const float* bz = bb + (size_t)z * N;
    const int t = threadIdx.x;
    constexpr int C = N >> 8;   // 4 or 2
    float vals[C];
    if (C == 4) {
        ushort4 u = ((const ushort4*)y)[t];
        vals[0] = bf2f(u.x); vals[1] = bf2f(u.y);
        vals[2] = bf2f(u.z); vals[3] = bf2f(u.w);
    } else {
        ushort2 u = ((const ushort2*)y)[t];
        vals[0] = bf2f(u.x); vals[1] = bf2f(u.y);
    }
    float s = 0.f, sq = 0.f;
    #pragma unroll
    for (int i = 0; i < C; ++i) { s += vals[i]; sq += vals[i] * vals[i]; }
    #pragma unroll
    for (int off = 32; off; off >>= 1) {
        s  += __shfl_xor(s,  off, 64);
        sq += __shfl_xor(sq, off, 64);
    }
    __shared__ float rs[4], rq[4];
    if ((t & 63) == 0) { rs[t >> 6] = s; rq[t >> 6] = sq; }
    __syncthreads();
    s  = rs[0] + rs[1] + rs[2] + rs[3];
    sq = rq[0] + rq[1] + rq[2] + rq[3];
    const float inv = 1.f / (float)N;
    const float mu  = s * inv;
    const float var = sq * inv - mu * mu;
    const float rstd = rsqrtf(var + 1e-5f);
    if (C == 4) {
        float4 gv = ((const float4*)gz)[t];
        float4 bv = ((const float4*)bz)[t];
        ushort4 o;
        o.x = f2bf(fmaxf((vals[0] - mu) * rstd * gv.x + bv.x, 0.f));
        o.y = f2bf(fmaxf((vals[1] - mu) * rstd * gv.y + bv.y, 0.f));
        o.z = f2bf(fmaxf((vals[2] - mu) * rstd * gv.z + bv.z, 0.f));
        o.w = f2bf(fmaxf((vals[3] - mu) * rstd * gv.w + bv.w, 0.f));
        ((ushort4*)y)[t] = o;
    } else {
        float2 gv = ((const float2*)gz)[t];
        float2 bv = ((const float2*)bz)[t];
        ushort2 o;
        o.x = f2bf(fmaxf((vals[0] - mu) * rstd * gv.x + bv.x, 0.f));
        o.y = f2bf(fmaxf((vals[1] - mu) * rstd * gv.y + bv.y, 0.f));
        ((ushort2*)y)[t] = o;
    }
}

// ---------------------------------------------------------------------------
// 2-class head + log_softmax, batched over z. 1 wave/row, vectorized loads.
// ---------------------------------------------------------------------------
__global__ __launch_bounds__(64) void head2_k(const u16* __restrict__ X, size_t xsz,
        const float* __restrict__ W, size_t wsz,
        const float* __restrict__ bias, size_t bsz,
        int K, float* __restrict__ out, size_t osz)
{
    const int b = blockIdx.x, z = blockIdx.y;
    const int lane = threadIdx.x;
    const u16* x = X + z * xsz + (size_t)b * K;
    const float* Wz = W + z * wsz;
    const float* bz = bias + z * bsz;
    float* o = out + z * osz + (size_t)b * 2;
    float p0 = 0.f, p1 = 0.f;
    for (int k8 = lane; k8 < (K >> 3); k8 += 64) {
        const uint4 raw = ((const uint4*)x)[k8];
        const u16* pu = (const u16*)&raw;
        const float4 w0 = ((const float4*)Wz)[k8 * 4 + 0];
        const float4 w1 = ((const float4*)Wz)[k8 * 4 + 1];
        const float4 w2 = ((const float4*)Wz)[k8 * 4 + 2];
        const float4 w3 = ((const float4*)Wz)[k8 * 4 + 3];
        p0 = fmaf(bf2f(pu[0]), w0.x, p0); p1 = fmaf(bf2f(pu[0]), w0.y, p1);
        p0 = fmaf(bf2f(pu[1]), w0.z, p0); p1 = fmaf(bf2f(pu[1]), w0.w, p1);
        p0 = fmaf(bf2f(pu[2]), w1.x, p0); p1 = fmaf(bf2f(pu[2]), w1.y, p1);
        p0 = fmaf(bf2f(pu[3]), w1.z, p0); p1 = fmaf(bf2f(pu[3]), w1.w, p1);
        p0 = fmaf(bf2f(pu[4]), w2.x, p0); p1 = fmaf(bf2f(pu[4]), w2.y, p1);
        p0 = fmaf(bf2f(pu[5]), w2.z, p0); p1 = fmaf(bf2f(pu[5]), w2.w, p1);
        p0 = fmaf(bf2f(pu[6]), w3.x, p0); p1 = fmaf(bf2f(pu[6]), w3.y, p1);
        p0 = fmaf(bf2f(pu[7]), w3.z, p0); p1 = fmaf(bf2f(pu[7]), w3.w, p1);
    }
    #pragma unroll
    for (int off = 32; off; off >>= 1) {
        p0 += __shfl_xor(p0, off, 64);
        p1 += __shfl_xor(p1, off, 64);
    }
    if (lane == 0) {
        const float l0 = p0 + bz[0];
        const float l1 = p1 + bz[1];
        const float mx = fmaxf(l0, l1);
        const float lse = mx + logf(expf(l0 - mx) + expf(l1 - mx));
        o[0] = l0 - lse;
        o[1] = l1 - lse;
    }
}

__global__ __launch_bounds__(256) void gather_k(const float* __restrict__ eo,
        const int* __restrict__ label, float* __restrict__ out, int B)
{
    const int b = blockIdx.x * 256 + threadIdx.x;
    if (b >= B) return;
    const int e = label[b];
    out[b * 2]     = eo[((size_t)e * B + b) * 2];
    out[b * 2 + 1] = eo[((size_t)e * B + b) * 2 + 1];
}

__global__ __launch_bounds__(256) void copy16_k(const uint4* __restrict__ in,
                                                uint4* __restrict__ out, int n16)
{
    const int i = blockIdx.x * blockDim.x + threadIdx.x;
    if (i < n16) out[i] = in[i];
}

// ---------------------------------------------------------------------------

extern "C" void kernel_launch(void* const* d_in, const int* in_sizes, int n_in,
                              void* d_out, int out_size, void* d_ws, size_t ws_size,
                              hipStream_t stream)
{
    const int B = 2048, D = 1280, E = 8;

    const float* src = (const float*)d_in[0];
    const float *bw1 = (const float*)d_in[1],  *bb1 = (const float*)d_in[2],
                *bg1 = (const float*)d_in[3],  *bbe1 = (const float*)d_in[4],
                *bm1 = (const float*)d_in[5],  *bv1 = (const float*)d_in[6];
    const float *bw2 = (const float*)d_in[7],  *bb2 = (const float*)d_in[8],
                *bg2 = (const float*)d_in[9],  *bbe2 = (const float*)d_in[10],
                *bm2 = (const float*)d_in[11], *bv2 = (const float*)d_in[12];
    const float *cw  = (const float*)d_in[13], *cb  = (const float*)d_in[14];
    const float *dw1 = (const float*)d_in[15], *db1 = (const float*)d_in[16],
                *dg1 = (const float*)d_in[17], *dbe1 = (const float*)d_in[18],
                *dm1 = (const float*)d_in[19], *dv1 = (const float*)d_in[20];
    const float *dw2 = (const float*)d_in[21], *db2 = (const float*)d_in[22],
                *dg2 = (const float*)d_in[23], *dbe2 = (const float*)d_in[24],
                *dm2 = (const float*)d_in[25], *dv2 = (const float*)d_in[26];
    const float *dw3 = (const float*)d_in[27], *db3 = (const float*)d_in[28],
                *dg3 = (const float*)d_in[29], *dbe3 = (const float*)d_in[30],
                *dm3 = (const float*)d_in[31], *dv3 = (const float*)d_in[32];
    const float *dw4 = (const float*)d_in[33], *db4 = (const float*)d_in[34];
    const float *ew1 = (const float*)d_in[35], *eb1 = (const float*)d_in[36],
                *eg1 = (const float*)d_in[37], *ebe1 = (const float*)d_in[38];
    const float *ew2 = (const float*)d_in[39], *eb2 = (const float*)d_in[40],
                *eg2 = (const float*)d_in[41], *ebe2 = (const float*)d_in[42];
    const float *ew3 = (const float*)d_in[43], *eb3 = (const float*)d_in[44],
                *eg3 = (const float*)d_in[45], *ebe3 = (const float*)d_in[46];
    const float *ew4 = (const float*)d_in[47], *eb4 = (const float*)d_in[48];

    float* out_src   = (float*)d_out;
    float* out_dclf  = out_src + B * E;
    float* out_sout  = out_dclf + B * 2;
    float* out_share = out_sout + B * 2;

    // ws layout (peak 60.44 MB):
    //   wslot [0, 13.11M)       bf16 JIT weights; during ROUTING ONLY this
    //                           region instead holds h2p f32 [4][2048][256]
    //                           (8.39M) + scs/shs (4KB @ 12.58M)
    //   srcb  [13.11M, 18.35M)  bf16 [2048][1280]
    //   acta  [18.35M, 39.32M)  bf16 5 x [2048][1024]  (hp f32 [4][2048][512] overlaps)
    //   actb  [39.32M, 60.29M)  bf16 5 x [2048][1024]
    //   eo    [60.29M, +128K) ; label [+8K)
    char* ws = (char*)d_ws;
    u16*   wslot = (u16*)ws;
    u16*   srcb  = (u16*)(ws + 13107200);
    u16*   acta  = (u16*)(ws + 18350080);
    u16*   actb  = (u16*)(ws + 39321600);
    float* eo    = (float*)(ws + 60293120);
    int*   label = (int*)(ws + 60424192);
    float* hp    = (float*)(ws + 18350080);   // overlaps acta; dead before experts
    float* h2p   = (float*)(ws);              // overlaps wslot; dead before convT
    float* scs   = (float*)(ws + 12582912);
    float* shs   = (float*)(ws + 12587008);

    const size_t s1024 = (size_t)B * 1024, s512 = (size_t)B * 512;

    // ---- src conversion + share passthrough ----
    conv_k<<<dim3(B * D / 8 / 256), 256, 0, stream>>>(src, srcb, B * D / 8);
    copy16_k<<<dim3(B * D * 4 / 16 / 256), 256, 0, stream>>>(
        (const uint4*)src, (uint4*)out_share, B * D * 4 / 16);

    // ---- routing: split-K f32 GEMMs + vectorized classifier tail ----
    bnpre_k<<<dim3(2), 256, 0, stream>>>(bg1, bbe1, bb1, bm1, bv1, scs, shs, 512);
    gemm_f32sk_k<<<dim3(512 / 64, B / 64, 4), 256, 0, stream>>>(
        src, bw1, hp, B, 512, D, 320);
    h2gemm_k<<<dim3(256 / 64, B / 64, 4), 256, 0, stream>>>(
        hp, scs, shs, bw2, h2p, B);
    cls_k<<<dim3(B / 4), 256, 0, stream>>>(
        h2p, bg2, bbe2, bb2, bm2, bv2, cw, cb, out_src, label, B);

    // ---- group A: experts 0..3 + domain classifier as z=4 ----
    convT2_k<<<dim3(16, 20, 5), 256, 0, stream>>>(ew1, dw1, 4, wslot, 1024, 1280);
    gemm_bt128_k<1><<<dim3(8, 16, 5), 256, 0, stream>>>(
        srcb, 0, wslot, eb1, db1, dg1, dbe1, dm1, dv1, 4, acta, B, 1024, 1280);
    ln_relu_k<1024><<<dim3(B, 4), 256, 0, stream>>>(acta, eg1, ebe1);

    convT2_k<<<dim3(16, 16, 5), 256, 0, stream>>>(ew2, dw2, 4, wslot, 1024, 1024);
    gemm_bt128_k<1><<<dim3(8, 16, 5), 256, 0, stream>>>(
        acta, s1024, wslot, eb2, db2, dg2, dbe2, dm2, dv2, 4, actb, B, 1024, 1024);
    ln_relu_k<1024><<<dim3(B, 4), 256, 0, stream>>>(actb, eg2, ebe2);

    convT2_k<<<dim3(8, 16, 5), 256, 0, stream>>>(ew3, dw3, 4, wslot, 512, 1024);
    gemm_bt128_k<1><<<dim3(4, 16, 5), 256, 0, stream>>>(
        actb, s1024, wslot, eb3, db3, dg3, dbe3, dm3, dv3, 4, acta, B, 512, 1024);
    ln_relu_k<512><<<dim3(B, 4), 256, 0, stream>>>(acta, eg3, ebe3);

    head2_k<<<dim3(B, 4), 64, 0, stream>>>(
        acta, s512, ew4, 1024, eb4, 2, 512, eo, (size_t)B * 2);
    head2_k<<<dim3(B, 1), 64, 0, stream>>>(
        acta + (size_t)4 * B * 512, 0, dw4, 0, db4, 0, 512, out_dclf, 0);

    // ---- group B: experts 4..7 ----
    convT2_k<<<dim3(16, 20, 4), 256, 0, stream>>>(
        ew1 + (size_t)4*1280*1024, ew1 + (size_t)4*1280*1024, 4, wslot, 1024, 1280);
    gemm_bt128_k<0><<<dim3(8, 16, 4), 256, 0, stream>>>(
        srcb, 0, wslot, eb1 + (size_t)4*1024,
        nullptr, nullptr, nullptr, nullptr, nullptr, -1, acta, B, 1024, 1280);
    ln_relu_k<1024><<<dim3(B, 4), 256, 0, stream>>>(acta, eg1 + (size_t)4*1024, ebe1 + (size_t)4*1024);

    convT2_k<<<dim3(16, 16, 4), 256, 0, stream>>>(
        ew2 + (size_t)4*1024*1024, ew2 + (size_t)4*1024*1024, 4, wslot, 1024, 1024);
    gemm_bt128_k<0><<<dim3(8, 16, 4), 256, 0, stream>>>(
        acta, s1024, wslot, eb2 + (size_t)4*1024,
        nullptr, nullptr, nullptr, nullptr, nullptr, -1, actb, B, 1024, 1024);
    ln_relu_k<1024><<<dim3(B, 4), 256, 0, stream>>>(actb, eg2 + (size_t)4*1024, ebe2 + (size_t)4*1024);

    convT2_k<<<dim3(8, 16, 4), 256, 0, stream>>>(
        ew3 + (size_t)4*1024*512, ew3 + (size_t)4*1024*512, 4, wslot, 512, 1024);
    gemm_bt128_k<0><<<dim3(4, 16, 4), 256, 0, stream>>>(
        actb, s1024, wslot, eb3 + (size_t)4*512,
        nullptr, nullptr, nullptr, nullptr, nullptr, -1, acta, B, 512, 1024);
    ln_relu_k<512><<<dim3(B, 4), 256, 0, stream>>>(acta, eg3 + (size_t)4*512, ebe3 + (size_t)4*512);

    head2_k<<<dim3(B, 4), 64, 0, stream>>>(
        acta, s512, ew4 + (size_t)4*512*2, 1024, eb4 + 8, 2, 512,
        eo + (size_t)4 * B * 2, (size_t)B * 2);

    gather_k<<<dim3(B / 256), 256, 0, stream>>>(eo, label, out_sout, B);
}

// Round 4
// 552.362 us; speedup vs baseline: 2.0960x; 1.0551x over previous
//
#include <hip/hip_runtime.h>

typedef unsigned short u16;
typedef short s8v __attribute__((ext_vector_type(8)));
typedef float f4v __attribute__((ext_vector_type(4)));

#define AS1 __attribute__((address_space(1)))
#define AS3 __attribute__((address_space(3)))

__device__ __forceinline__ float bf2f(u16 u) {
    union { unsigned int i; float f; } x; x.i = ((unsigned int)u) << 16; return x.f;
}
__device__ __forceinline__ u16 f2bf(float f) {
    union { float f; unsigned int i; } x; x.f = f;
    unsigned int r = x.i + 0x7fffu + ((x.i >> 16) & 1u);
    return (u16)(r >> 16);
}

// async global->LDS, 16B per lane; LDS dest = wave-uniform base + lane*16
__device__ __forceinline__ void glds16(const u16* g, u16* l) {
    __builtin_amdgcn_global_load_lds((AS1 void*)(g), (AS3 void*)(l), 16, 0, 0);
}

// swizzled LDS element offset for a [row][64] bf16 tile, kq multiple of 8.
__device__ __forceinline__ int swz(int row, int kq) {
    return row * 64 + ((((kq >> 3) ^ row) & 7) << 3);
}

// ---------------------------------------------------------------------------
// Weight convert+transpose: W f32 [K][N] -> WT bf16 [N][K]. Batched over z;
// z < zSplit reads Wa[z], else Wb[z-zSplit].
// ---------------------------------------------------------------------------
__global__ __launch_bounds__(256) void convT2_k(const float* __restrict__ Wa,
        const float* __restrict__ Wb, int zSplit,
        u16* __restrict__ WT, int N, int K)
{
    const int z = blockIdx.z;
    const float* W = (z < zSplit) ? Wa + (size_t)z * K * N
                                  : Wb + (size_t)(z - zSplit) * K * N;
    WT += (size_t)z * K * N;
    const int n0 = blockIdx.x * 64, k0 = blockIdx.y * 64;
    __shared__ float t[64][65];
    const int r = threadIdx.x >> 2;          // 0..63
    const int c = (threadIdx.x & 3) << 4;    // 0,16,32,48
    const float* wp = W + (size_t)(k0 + r) * N + n0 + c;
    #pragma unroll
    for (int q = 0; q < 16; q += 4) {
        float4 f = *(const float4*)(wp + q);
        t[c + q + 0][r] = f.x; t[c + q + 1][r] = f.y;
        t[c + q + 2][r] = f.z; t[c + q + 3][r] = f.w;
    }
    __syncthreads();
    u16* op = WT + (size_t)(n0 + r) * K + k0 + c;
    #pragma unroll
    for (int q = 0; q < 16; q += 8) {
        s8v v;
        #pragma unroll
        for (int j = 0; j < 8; ++j) v[j] = (short)f2bf(t[r][c + q + j]);
        *(s8v*)(op + q) = v;
    }
}

// ---------------------------------------------------------------------------
// src: f32 -> bf16 (srcb) and f32 passthrough (out_share), one read.
// ---------------------------------------------------------------------------
__global__ __launch_bounds__(256) void convsrc_k(const float* __restrict__ in,
        u16* __restrict__ outb, float* __restrict__ outf, int n8)
{
    const int i = blockIdx.x * 256 + threadIdx.x;
    if (i >= n8) return;
    const float4 f0 = ((const float4*)in)[i * 2];
    const float4 f1 = ((const float4*)in)[i * 2 + 1];
    s8v v;
    v[0]=(short)f2bf(f0.x); v[1]=(short)f2bf(f0.y);
    v[2]=(short)f2bf(f0.z); v[3]=(short)f2bf(f0.w);
    v[4]=(short)f2bf(f1.x); v[5]=(short)f2bf(f1.y);
    v[6]=(short)f2bf(f1.z); v[7]=(short)f2bf(f1.w);
    ((s8v*)outb)[i] = v;
    ((float4*)outf)[i * 2]     = f0;
    ((float4*)outf)[i * 2 + 1] = f1;
}

// ---------------------------------------------------------------------------
// Batched bf16 GEMM, 128x128 tile, T2 swizzle, 2-deep counted-vmcnt pipeline
// (raw s_barrier; vmcnt(8) in steady state, never 0 until the last tile).
// ---------------------------------------------------------------------------
__device__ __forceinline__ void stage_tile(u16* AsH, u16* BsH,
        const u16* ga, const u16* gb, int kk, int ldsq, int K)
{
    #pragma unroll
    for (int q = 0; q < 4; ++q) {
        glds16(ga + kk + (size_t)q * 32 * K, AsH + q * 2048 + ldsq);
        glds16(gb + kk + (size_t)q * 32 * K, BsH + q * 2048 + ldsq);
    }
}

template<int HASDOM>
__global__ __launch_bounds__(256) void gemm_bt128_k(
    const u16* __restrict__ A0, size_t aStrideZ,
    const u16* __restrict__ WT0,
    const float* __restrict__ ebias,
    const float* __restrict__ dbias, const float* __restrict__ dgam,
    const float* __restrict__ dbet,  const float* __restrict__ dmean,
    const float* __restrict__ dvar,  int zdom,
    u16* __restrict__ out0, int M, int N, int K)
{
    const int z = blockIdx.z;
    const u16* A  = A0  + (size_t)z * aStrideZ;
    const u16* WT = WT0 + (size_t)z * N * K;
    u16* out = out0 + (size_t)z * M * N;

    const int n0 = blockIdx.x * 128, m0 = blockIdx.y * 128;
    const int t = threadIdx.x;
    const int w = t >> 6, lane = t & 63;
    const int lq = lane >> 4, lr = lane & 15;
    const int wm = (w >> 1) * 64, wn = (w & 1) * 64;

    __shared__ __align__(16) u16 As[2 * 128 * 64];
    __shared__ __align__(16) u16 Bs[2 * 128 * 64];

    f4v acc[4][4] = {};

    const int schunk = ((t & 7) ^ ((t >> 3) & 7)) << 3;
    const u16* ga = A  + (size_t)(m0 + (t >> 3)) * K + schunk;
    const u16* gb = WT + (size_t)(n0 + (t >> 3)) * K + schunk;
    const int ldsq = w * 512;   // elements

    const int NT = K >> 6;
    // 2-deep prologue
    stage_tile(As, Bs, ga, gb, 0, ldsq, K);
    if (NT > 1) stage_tile(As + 8192, Bs + 8192, ga, gb, 64, ldsq, K);

    for (int tk = 0; tk < NT; ++tk) {
        // wait only the OLDER 8 loads (tile tk); tile tk+1's stay in flight
        if (tk < NT - 1) asm volatile("s_waitcnt vmcnt(8)" ::: "memory");
        else             asm volatile("s_waitcnt vmcnt(0)" ::: "memory");
        __builtin_amdgcn_s_barrier();
        __builtin_amdgcn_sched_barrier(0);

        const u16* Ah = As + (tk & 1) * 8192;
        const u16* Bh = Bs + (tk & 1) * 8192;
        __builtin_amdgcn_s_setprio(1);
        #pragma unroll
        for (int ks = 0; ks < 64; ks += 32) {
            const int kq = ks + (lq << 3);
            s8v a[4], b[4];
            #pragma unroll
            for (int i = 0; i < 4; ++i) a[i] = *(const s8v*)&Ah[swz(wm + i*16 + lr, kq)];
            #pragma unroll
            for (int j = 0; j < 4; ++j) b[j] = *(const s8v*)&Bh[swz(wn + j*16 + lr, kq)];
            #pragma unroll
            for (int i = 0; i < 4; ++i)
                #pragma unroll
                for (int j = 0; j < 4; ++j)
                    acc[i][j] = __builtin_amdgcn_mfma_f32_16x16x32_bf16(a[i], b[j], acc[i][j], 0, 0, 0);
        }
        __builtin_amdgcn_s_setprio(0);
        __builtin_amdgcn_sched_barrier(0);
        __builtin_amdgcn_s_barrier();   // all waves done reading buf[tk&1]

        if (tk + 2 < NT)
            stage_tile(As + (tk & 1) * 8192, Bs + (tk & 1) * 8192,
                       ga, gb, (tk + 2) << 6, ldsq, K);
    }

    float scale[4], shift[4];
    const bool dom = HASDOM && (z == zdom);
    #pragma unroll
    for (int j = 0; j < 4; ++j) {
        const int c = n0 + wn + j * 16 + lr;
        if (dom) {
            const float s = dgam[c] / sqrtf(dvar[c] + 1e-5f);
            scale[j] = s;
            shift[j] = (dbias[c] - dmean[c]) * s + dbet[c];
        } else {
            scale[j] = 1.f;
            shift[j] = ebias[(size_t)z * N + c];
        }
    }
    const int r0 = lq << 2;
    #pragma unroll
    for (int i = 0; i < 4; ++i) {
        #pragma unroll
        for (int r = 0; r < 4; ++r) {
            const int grow = m0 + wm + i * 16 + r0 + r;
            u16* orow = out + (size_t)grow * N + n0 + wn + lr;
            #pragma unroll
            for (int j = 0; j < 4; ++j) {
                float y = fmaf(acc[i][j][r], scale[j], shift[j]);
                if (dom) y = fmaxf(y, 0.f);
                orow[j * 16] = f2bf(y);
            }
        }
    }
}

// ---------------------------------------------------------------------------
// f32-exact split-K GEMM (routing h1 partials, no epilogue).
// ---------------------------------------------------------------------------
__global__ __launch_bounds__(256) void gemm_f32sk_k(
    const float* __restrict__ A, const float* __restrict__ W,
    float* __restrict__ out, int M, int N, int K, int Ks)
{
    const int n0 = blockIdx.x * 64, m0 = blockIdx.y * 64;
    const int kb = blockIdx.z * Ks;
    out += (size_t)blockIdx.z * M * N;
    const int tid = threadIdx.x;
    const int tx = tid & 15, ty = tid >> 4;
    __shared__ float As[64][65];
    __shared__ float Bs[64][64];
    float acc[4][4] = {};
    const int sr = tid >> 2;
    const int sc = (tid & 3) << 4;
    for (int kk = kb; kk < kb + Ks; kk += 64) {
        const float* ap = A + (size_t)(m0 + sr) * K + kk + sc;
        #pragma unroll
        for (int q = 0; q < 4; ++q) {
            float4 f = *(const float4*)(ap + q * 4);
            As[sr][sc + q*4 + 0] = f.x; As[sr][sc + q*4 + 1] = f.y;
            As[sr][sc + q*4 + 2] = f.z; As[sr][sc + q*4 + 3] = f.w;
        }
        const float* wp = W + (size_t)(kk + sr) * N + n0 + sc;
        #pragma unroll
        for (int q = 0; q < 4; ++q)
            *(float4*)&Bs[sr][sc + q*4] = *(const float4*)(wp + q * 4);
        __syncthreads();
        #pragma unroll 4
        for (int kq = 0; kq < 64; ++kq) {
            float a[4], bv[4];
            #pragma unroll
            for (int i = 0; i < 4; ++i) a[i] = As[ty*4 + i][kq];
            #pragma unroll
            for (int j = 0; j < 4; ++j) bv[j] = Bs[kq][tx*4 + j];
            #pragma unroll
            for (int i = 0; i < 4; ++i)
                #pragma unroll
                for (int j = 0; j < 4; ++j)
                    acc[i][j] = fmaf(a[i], bv[j], acc[i][j]);
        }
        __syncthreads();
    }
    #pragma unroll
    for (int j = 0; j < 4; ++j) {
        const int c = n0 + tx*4 + j;
        #pragma unroll
        for (int i = 0; i < 4; ++i)
            out[(size_t)(m0 + ty*4 + i) * N + c] = acc[i][j];
    }
}

// ---------------------------------------------------------------------------
// Routing h2 GEMM, split-K=4, BN1 precompute fused (per-block k-range).
// A = BN1+ReLU(combine4(hp)) on the fly; B = bw2 [512][256].
// ---------------------------------------------------------------------------
__global__ __launch_bounds__(256) void h2gemm_k(
    const float* __restrict__ hp,
    const float* __restrict__ bg1, const float* __restrict__ bbe1,
    const float* __restrict__ bb1, const float* __restrict__ bm1,
    const float* __restrict__ bv1,
    const float* __restrict__ bw2,
    float* __restrict__ out, int B)
{
    const int n0 = blockIdx.x * 64, m0 = blockIdx.y * 64;
    const int kb = blockIdx.z * 128;
    out += (size_t)blockIdx.z * B * 256;
    const size_t sl = (size_t)B * 512;
    const int tid = threadIdx.x;
    const int tx = tid & 15, ty = tid >> 4;
    __shared__ float As[64][65];
    __shared__ float Bs[64][64];
    __shared__ __align__(16) float scl[128], shl[128];
    if (tid < 128) {
        const int k = kb + tid;
        const float sc = bg1[k] / sqrtf(bv1[k] + 1e-5f);
        scl[tid] = sc;
        shl[tid] = (bb1[k] - bm1[k]) * sc + bbe1[k];
    }
    __syncthreads();
    float acc[4][4] = {};
    const int sr = tid >> 2;
    const int sc = (tid & 3) << 4;
    for (int kk = kb; kk < kb + 128; kk += 64) {
        const int kl = kk - kb;
        const float* ap = hp + (size_t)(m0 + sr) * 512 + kk + sc;
        #pragma unroll
        for (int q = 0; q < 4; ++q) {
            const float4 f0 = *(const float4*)(ap + q * 4);
            const float4 f1 = *(const float4*)(ap + sl + q * 4);
            const float4 f2 = *(const float4*)(ap + 2 * sl + q * 4);
            const float4 f3 = *(const float4*)(ap + 3 * sl + q * 4);
            const float4 g = *(const float4*)&scl[kl + sc + q * 4];
            const float4 h = *(const float4*)&shl[kl + sc + q * 4];
            As[sr][sc + q*4 + 0] = fmaxf(fmaf(f0.x + f1.x + f2.x + f3.x, g.x, h.x), 0.f);
            As[sr][sc + q*4 + 1] = fmaxf(fmaf(f0.y + f1.y + f2.y + f3.y, g.y, h.y), 0.f);
            As[sr][sc + q*4 + 2] = fmaxf(fmaf(f0.z + f1.z + f2.z + f3.z, g.z, h.z), 0.f);
            As[sr][sc + q*4 + 3] = fmaxf(fmaf(f0.w + f1.w + f2.w + f3.w, g.w, h.w), 0.f);
        }
        const float* wp = bw2 + (size_t)(kk + sr) * 256 + n0 + sc;
        #pragma unroll
        for (int q = 0; q < 4; ++q)
            *(float4*)&Bs[sr][sc + q*4] = *(const float4*)(wp + q * 4);
        __syncthreads();
        #pragma unroll 4
        for (int kq = 0; kq < 64; ++kq) {
            float a[4], bv[4];
            #pragma unroll
            for (int i = 0; i < 4; ++i) a[i] = As[ty*4 + i][kq];
            #pragma unroll
            for (int j = 0; j < 4; ++j) bv[j] = Bs[kq][tx*4 + j];
            #pragma unroll
            for (int i = 0; i < 4; ++i)
                #pragma unroll
                for (int j = 0; j < 4; ++j)
                    acc[i][j] = fmaf(a[i], bv[j], acc[i][j]);
        }
        __syncthreads();
    }
    #pragma unroll
    for (int j = 0; j < 4; ++j) {
        const int c = n0 + tx*4 + j;
        #pragma unroll
        for (int i = 0; i < 4; ++i)
            out[(size_t)(m0 + ty*4 + i) * 256 + c] = acc[i][j];
    }
}

// ---------------------------------------------------------------------------
// Routing classifier tail (unchanged from round 3).
// ---------------------------------------------------------------------------
__global__ __launch_bounds__(256) void cls_k(
    const float* __restrict__ h2p,
    const float* __restrict__ bg2, const float* __restrict__ bbe2,
    const float* __restrict__ bb2, const float* __restrict__ bm2,
    const float* __restrict__ bv2,
    const float* __restrict__ cw,  const float* __restrict__ cb,
    float* __restrict__ out_src, int* __restrict__ label, int B)
{
    const int b = blockIdx.x * 4 + (threadIdx.x >> 6);
    const int lane = threadIdx.x & 63;
    const size_t sl = (size_t)B * 256;
    const float* hb = h2p + (size_t)b * 256 + lane * 4;
    const float4 v0 = *(const float4*)(hb);
    const float4 v1 = *(const float4*)(hb + sl);
    const float4 v2 = *(const float4*)(hb + 2 * sl);
    const float4 v3 = *(const float4*)(hb + 3 * sl);
    const float4 gv = ((const float4*)bg2)[lane];
    const float4 vv = ((const float4*)bv2)[lane];
    const float4 bbv = ((const float4*)bb2)[lane];
    const float4 bmv = ((const float4*)bm2)[lane];
    const float4 bev = ((const float4*)bbe2)[lane];
    float h[4];
    {
        const float s0 = gv.x / sqrtf(vv.x + 1e-5f);
        const float s1 = gv.y / sqrtf(vv.y + 1e-5f);
        const float s2 = gv.z / sqrtf(vv.z + 1e-5f);
        const float s3 = gv.w / sqrtf(vv.w + 1e-5f);
        h[0] = fmaxf(fmaf(v0.x + v1.x + v2.x + v3.x, s0, (bbv.x - bmv.x) * s0 + bev.x), 0.f);
        h[1] = fmaxf(fmaf(v0.y + v1.y + v2.y + v3.y, s1, (bbv.y - bmv.y) * s1 + bev.y), 0.f);
        h[2] = fmaxf(fmaf(v0.z + v1.z + v2.z + v3.z, s2, (bbv.z - bmv.z) * s2 + bev.z), 0.f);
        h[3] = fmaxf(fmaf(v0.w + v1.w + v2.w + v3.w, s3, (bbv.w - bmv.w) * s3 + bev.w), 0.f);
    }
    float p[8] = {};
    #pragma unroll
    for (int j = 0; j < 4; ++j) {
        const float4 c0 = ((const float4*)cw)[(lane * 4 + j) * 2];
        const float4 c1 = ((const float4*)cw)[(lane * 4 + j) * 2 + 1];
        p[0] = fmaf(h[j], c0.x, p[0]); p[1] = fmaf(h[j], c0.y, p[1]);
        p[2] = fmaf(h[j], c0.z, p[2]); p[3] = fmaf(h[j], c0.w, p[3]);
        p[4] = fmaf(h[j], c1.x, p[4]); p[5] = fmaf(h[j], c1.y, p[5]);
        p[6] = fmaf(h[j], c1.z, p[6]); p[7] = fmaf(h[j], c1.w, p[7]);
    }
    #pragma unroll
    for (int off = 32; off; off >>= 1)
        #pragma unroll
        for (int c = 0; c < 8; ++c) p[c] += __shfl_xor(p[c], off, 64);
    if (lane == 0) {
        float lg[8];
        #pragma unroll
        for (int c = 0; c < 8; ++c) lg[c] = p[c] + cb[c];
        float mx = lg[0]; int am = 0;
        #pragma unroll
        for (int c = 1; c < 8; ++c) if (lg[c] > mx) { mx = lg[c]; am = c; }
        float ssum = 0.f;
        #pragma unroll
        for (int c = 0; c < 8; ++c) ssum += expf(lg[c] - mx);
        const float lse = mx + logf(ssum);
        #pragma unroll
        for (int c = 0; c < 8; ++c) out_src[b * 8 + c] = lg[c] - lse;
        label[b] = am;
    }
}

// ---------------------------------------------------------------------------
// In-place LayerNorm + ReLU, batched over z (grid.y). N=1024 only now.
// ---------------------------------------------------------------------------
template<int N>
__global__ __launch_bounds__(256) void ln_relu_k(u16* __restrict__ Y,
        const float* __restrict__ g, const float* __restrict__ bb)
{
    const int z = blockIdx.y;
    u16* y = Y + ((size_t)z * gridDim.x + blockIdx.x) * N;
    const float* gz = g  + (size_t)z * N;
    const float* bz = bb + (size_t)z * N;
    const int t = threadIdx.x;
    constexpr int C = N >> 8;
    float vals[C];
    ushort4 u = ((const ushort4*)y)[t];
    vals[0] = bf2f(u.x); vals[1] = bf2f(u.y);
    vals[2] = bf2f(u.z); vals[3] = bf2f(u.w);
    float s = 0.f, sq = 0.f;
    #pragma unroll
    for (int i = 0; i < C; ++i) { s += vals[i]; sq += vals[i] * vals[i]; }
    #pragma unroll
    for (int off = 32; off; off >>= 1) {
        s  += __shfl_xor(s,  off, 64);
        sq += __shfl_xor(sq, off, 64);
    }
    __shared__ float rs[4], rq[4];
    if ((t & 63) == 0) { rs[t >> 6] = s; rq[t >> 6] = sq; }
    __syncthreads();
    s  = rs[0] + rs[1] + rs[2] + rs[3];
    sq = rq[0] + rq[1] + rq[2] + rq[3];
    const float inv = 1.f / (float)N;
    const float mu  = s * inv;
    const float var = sq * inv - mu * mu;
    const float rstd = rsqrtf(var + 1e-5f);
    float4 gv = ((const float4*)gz)[t];
    float4 bv = ((const float4*)bz)[t];
    ushort4 o;
    o.x = f2bf(fmaxf((vals[0] - mu) * rstd * gv.x + bv.x, 0.f));
    o.y = f2bf(fmaxf((vals[1] - mu) * rstd * gv.y + bv.y, 0.f));
    o.z = f2bf(fmaxf((vals[2] - mu) * rstd * gv.z + bv.z, 0.f));
    o.w = f2bf(fmaxf((vals[3] - mu) * rstd * gv.w + bv.w, 0.f));
    ((ushort4*)y)[t] = o;
}

// ---------------------------------------------------------------------------
// Selected-expert head: LN(512) + ReLU + 512->2 matvec + log_softmax for the
// ONE expert chosen by label[b]. X holds raw L3 GEMM output (+bias).
// One wave per sample; lane owns 8 contiguous elements.
// ---------------------------------------------------------------------------
__global__ __launch_bounds__(64) void headsel_k(
    const u16* __restrict__ X,        // [4][B][512] slots zBase..zBase+3
    const int* __restrict__ label,
    const float* __restrict__ eg3, const float* __restrict__ ebe3,  // [8][512]
    const float* __restrict__ ew4, const float* __restrict__ eb4,   // [8][512][2],[8][2]
    int zBase, float* __restrict__ out_sout, int B)
{
    const int b = blockIdx.x;
    const int e = label[b];
    if (e < zBase || e >= zBase + 4) return;
    const int lane = threadIdx.x;
    const u16* x = X + ((size_t)(e - zBase) * B + b) * 512 + lane * 8;
    uint4 raw = *(const uint4*)x;
    const u16* pu = (const u16*)&raw;
    float v[8];
    #pragma unroll
    for (int i = 0; i < 8; ++i) v[i] = bf2f(pu[i]);
    float s = 0.f, sq = 0.f;
    #pragma unroll
    for (int i = 0; i < 8; ++i) { s += v[i]; sq += v[i] * v[i]; }
    #pragma unroll
    for (int off = 32; off; off >>= 1) {
        s  += __shfl_xor(s,  off, 64);
        sq += __shfl_xor(sq, off, 64);
    }
    const float mu = s * (1.f / 512.f);
    const float var = sq * (1.f / 512.f) - mu * mu;
    const float rstd = rsqrtf(var + 1e-5f);
    const float* g  = eg3  + (size_t)e * 512 + lane * 8;
    const float* be = ebe3 + (size_t)e * 512 + lane * 8;
    const float4 g0 = *(const float4*)g,  g1 = *(const float4*)(g + 4);
    const float4 b0 = *(const float4*)be, b1 = *(const float4*)(be + 4);
    float h[8];
    h[0] = fmaxf((v[0]-mu)*rstd*g0.x + b0.x, 0.f);
    h[1] = fmaxf((v[1]-mu)*rstd*g0.y + b0.y, 0.f);
    h[2] = fmaxf((v[2]-mu)*rstd*g0.z + b0.z, 0.f);
    h[3] = fmaxf((v[3]-mu)*rstd*g0.w + b0.w, 0.f);
    h[4] = fmaxf((v[4]-mu)*rstd*g1.x + b1.x, 0.f);
    h[5] = fmaxf((v[5]-mu)*rstd*g1.y + b1.y, 0.f);
    h[6] = fmaxf((v[6]-mu)*rstd*g1.z + b1.z, 0.f);
    h[7] = fmaxf((v[7]-mu)*rstd*g1.w + b1.w, 0.f);
    const float* W = ew4 + (size_t)e * 1024 + lane * 16;
    float p0 = 0.f, p1 = 0.f;
    #pragma unroll
    for (int q = 0; q < 4; ++q) {
        const float4 wv = *(const float4*)(W + q * 4);
        p0 = fmaf(h[q*2],   wv.x, p0); p1 = fmaf(h[q*2],   wv.y, p1);
        p0 = fmaf(h[q*2+1], wv.z, p0); p1 = fmaf(h[q*2+1], wv.w, p1);
    }
    #pragma unroll
    for (int off = 32; off; off >>= 1) {
        p0 += __shfl_xor(p0, off, 64);
        p1 += __shfl_xor(p1, off, 64);
    }
    if (lane == 0) {
        const float l0 = p0 + eb4[e * 2];
        const float l1 = p1 + eb4[e * 2 + 1];
        const float mx = fmaxf(l0, l1);
        const float lse = mx + logf(expf(l0 - mx) + expf(l1 - mx));
        out_sout[b * 2]     = l0 - lse;
        out_sout[b * 2 + 1] = l1 - lse;
    }
}

// ---------------------------------------------------------------------------
// Domain 2-class head + log_softmax (BN+ReLU already applied). 1 wave/row.
// ---------------------------------------------------------------------------
__global__ __launch_bounds__(64) void head2_k(const u16* __restrict__ X,
        const float* __restrict__ W, const float* __restrict__ bias,
        float* __restrict__ out)
{
    const int b = blockIdx.x;
    const int lane = threadIdx.x;
    const u16* x = X + (size_t)b * 512 + lane * 8;
    uint4 raw = *(const uint4*)x;
    const u16* pu = (const u16*)&raw;
    const float* Wz = W + lane * 16;
    float p0 = 0.f, p1 = 0.f;
    #pragma unroll
    for (int q = 0; q < 4; ++q) {
        const float4 wv = *(const float4*)(Wz + q * 4);
        p0 = fmaf(bf2f(pu[q*2]),   wv.x, p0); p1 = fmaf(bf2f(pu[q*2]),   wv.y, p1);
        p0 = fmaf(bf2f(pu[q*2+1]), wv.z, p0); p1 = fmaf(bf2f(pu[q*2+1]), wv.w, p1);
    }
    #pragma unroll
    for (int off = 32; off; off >>= 1) {
        p0 += __shfl_xor(p0, off, 64);
        p1 += __shfl_xor(p1, off, 64);
    }
    if (lane == 0) {
        const float l0 = p0 + bias[0];
        const float l1 = p1 + bias[1];
        const float mx = fmaxf(l0, l1);
        const float lse = mx + logf(expf(l0 - mx) + expf(l1 - mx));
        out[b * 2]     = l0 - lse;
        out[b * 2 + 1] = l1 - lse;
    }
}

// ---------------------------------------------------------------------------

extern "C" void kernel_launch(void* const* d_in, const int* in_sizes, int n_in,
                              void* d_out, int out_size, void* d_ws, size_t ws_size,
                              hipStream_t stream)
{
    const int B = 2048, D = 1280, E = 8;

    const float* src = (const float*)d_in[0];
    const float *bw1 = (const float*)d_in[1],  *bb1 = (const float*)d_in[2],
                *bg1 = (const float*)d_in[3],  *bbe1 = (const float*)d_in[4],
                *bm1 = (const float*)d_in[5],  *bv1 = (const float*)d_in[6];
    const float *bw2 = (const float*)d_in[7],  *bb2 = (const float*)d_in[8],
                *bg2 = (const float*)d_in[9],  *bbe2 = (const float*)d_in[10],
                *bm2 = (const float*)d_in[11], *bv2 = (const float*)d_in[12];
    const float *cw  = (const float*)d_in[13], *cb  = (const float*)d_in[14];
    const float *dw1 = (const float*)d_in[15], *db1 = (const float*)d_in[16],
                *dg1 = (const float*)d_in[17], *dbe1 = (const float*)d_in[18],
                *dm1 = (const float*)d_in[19], *dv1 = (const float*)d_in[20];
    const float *dw2 = (const float*)d_in[21], *db2 = (const float*)d_in[22],
                *dg2 = (const float*)d_in[23], *dbe2 = (const float*)d_in[24],
                *dm2 = (const float*)d_in[25], *dv2 = (const float*)d_in[26];
    const float *dw3 = (const float*)d_in[27], *db3 = (const float*)d_in[28],
                *dg3 = (const float*)d_in[29], *dbe3 = (const float*)d_in[30],
                *dm3 = (const float*)d_in[31], *dv3 = (const float*)d_in[32];
    const float *dw4 = (const float*)d_in[33], *db4 = (const float*)d_in[34];
    const float *ew1 = (const float*)d_in[35], *eb1 = (const float*)d_in[36],
                *eg1 = (const float*)d_in[37], *ebe1 = (const float*)d_in[38];
    const float *ew2 = (const float*)d_in[39], *eb2 = (const float*)d_in[40],
                *eg2 = (const float*)d_in[41], *ebe2 = (const float*)d_in[42];
    const float *ew3 = (const float*)d_in[43], *eb3 = (const float*)d_in[44],
                *eg3 = (const float*)d_in[45], *ebe3 = (const float*)d_in[46];
    const float *ew4 = (const float*)d_in[47], *eb4 = (const float*)d_in[48];

    float* out_src   = (float*)d_out;
    float* out_dclf  = out_src + B * E;
    float* out_sout  = out_dclf + B * 2;
    float* out_share = out_sout + B * 2;

    // ws layout (peak 60.3 MB):
    //   wslot [0, 13.11M)       bf16 JIT weights; during ROUTING holds
    //                           h2p f32 [4][2048][256] (8.39M)
    //   srcb  [13.11M, 18.35M)  bf16 [2048][1280]
    //   acta  [18.35M, 39.32M)  bf16 5 x [2048][1024] (hp f32 [4][2048][512] overlaps)
    //   actb  [39.32M, 60.29M)  bf16 5 x [2048][1024]
    //   label [60.29M, +8K)
    char* ws = (char*)d_ws;
    u16*   wslot = (u16*)ws;
    u16*   srcb  = (u16*)(ws + 13107200);
    u16*   acta  = (u16*)(ws + 18350080);
    u16*   actb  = (u16*)(ws + 39321600);
    int*   label = (int*)(ws + 60293120);
    float* hp    = (float*)(ws + 18350080);   // overlaps acta; dead before experts
    float* h2p   = (float*)(ws);              // overlaps wslot; dead before convT

    const size_t s1024 = (size_t)B * 1024, s512 = (size_t)B * 512;

    // ---- src conversion + share passthrough (single pass) ----
    convsrc_k<<<dim3(B * D / 8 / 256), 256, 0, stream>>>(src, srcb, out_share, B * D / 8);

    // ---- routing ----
    gemm_f32sk_k<<<dim3(512 / 64, B / 64, 4), 256, 0, stream>>>(
        src, bw1, hp, B, 512, D, 320);
    h2gemm_k<<<dim3(256 / 64, B / 64, 4), 256, 0, stream>>>(
        hp, bg1, bbe1, bb1, bm1, bv1, bw2, h2p, B);
    cls_k<<<dim3(B / 4), 256, 0, stream>>>(
        h2p, bg2, bbe2, bb2, bm2, bv2, cw, cb, out_src, label, B);

    // ---- group A: experts 0..3 + domain classifier as z=4 ----
    convT2_k<<<dim3(16, 20, 5), 256, 0, stream>>>(ew1, dw1, 4, wslot, 1024, 1280);
    gemm_bt128_k<1><<<dim3(8, 16, 5), 256, 0, stream>>>(
        srcb, 0, wslot, eb1, db1, dg1, dbe1, dm1, dv1, 4, acta, B, 1024, 1280);
    ln_relu_k<1024><<<dim3(B, 4), 256, 0, stream>>>(acta, eg1, ebe1);

    convT2_k<<<dim3(16, 16, 5), 256, 0, stream>>>(ew2, dw2, 4, wslot, 1024, 1024);
    gemm_bt128_k<1><<<dim3(8, 16, 5), 256, 0, stream>>>(
        acta, s1024, wslot, eb2, db2, dg2, dbe2, dm2, dv2, 4, actb, B, 1024, 1024);
    ln_relu_k<1024><<<dim3(B, 4), 256, 0, stream>>>(actb, eg2, ebe2);

    convT2_k<<<dim3(8, 16, 5), 256, 0, stream>>>(ew3, dw3, 4, wslot, 512, 1024);
    gemm_bt128_k<1><<<dim3(4, 16, 5), 256, 0, stream>>>(
        actb, s1024, wslot, eb3, db3, dg3, dbe3, dm3, dv3, 4, acta, B, 512, 1024);

    headsel_k<<<dim3(B), 64, 0, stream>>>(
        acta, label, eg3, ebe3, ew4, eb4, 0, out_sout, B);
    head2_k<<<dim3(B), 64, 0, stream>>>(
        acta + (size_t)4 * s512, dw4, db4, out_dclf);

    // ---- group B: experts 4..7 ----
    convT2_k<<<dim3(16, 20, 4), 256, 0, stream>>>(
        ew1 + (size_t)4*1280*1024, ew1 + (size_t)4*1280*1024, 4, wslot, 1024, 1280);
    gemm_bt128_k<0><<<dim3(8, 16, 4), 256, 0, stream>>>(
        srcb, 0, wslot, eb1 + (size_t)4*1024,
        nullptr, nullptr, nullptr, nullptr, nullptr, -1, acta, B, 1024, 1280);
    ln_relu_k<1024><<<dim3(B, 4), 256, 0, stream>>>(acta, eg1 + (size_t)4*1024, ebe1 + (size_t)4*1024);

    convT2_k<<<dim3(16, 16, 4), 256, 0, stream>>>(
        ew2 + (size_t)4*1024*1024, ew2 + (size_t)4*1024*1024, 4, wslot, 1024, 1024);
    gemm_bt128_k<0><<<dim3(8, 16, 4), 256, 0, stream>>>(
        acta, s1024, wslot, eb2 + (size_t)4*1024,
        nullptr, nullptr, nullptr, nullptr, nullptr, -1, actb, B, 1024, 1024);
    ln_relu_k<1024><<<dim3(B, 4), 256, 0, stream>>>(actb, eg2 + (size_t)4*1024, ebe2 + (size_t)4*1024);

    convT2_k<<<dim3(8, 16, 4), 256, 0, stream>>>(
        ew3 + (size_t)4*1024*512, ew3 + (size_t)4*1024*512, 4, wslot, 512, 1024);
    gemm_bt128_k<0><<<dim3(4, 16, 4), 256, 0, stream>>>(
        actb, s1024, wslot, eb3 + (size_t)4*512,
        nullptr, nullptr, nullptr, nullptr, nullptr, -1, acta, B, 512, 1024);

    headsel_k<<<dim3(B), 64, 0, stream>>>(
        acta, label, eg3, ebe3, ew4, eb4, 4, out_sout, B);
}

// Round 6
// 538.860 us; speedup vs baseline: 2.1485x; 1.0251x over previous
//
#include <hip/hip_runtime.h>

typedef unsigned short u16;
typedef short s8v __attribute__((ext_vector_type(8)));
typedef float f4v __attribute__((ext_vector_type(4)));

#define AS1 __attribute__((address_space(1)))
#define AS3 __attribute__((address_space(3)))

__device__ __forceinline__ float bf2f(u16 u) {
    union { unsigned int i; float f; } x; x.i = ((unsigned int)u) << 16; return x.f;
}
__device__ __forceinline__ u16 f2bf(float f) {
    union { float f; unsigned int i; } x; x.f = f;
    unsigned int r = x.i + 0x7fffu + ((x.i >> 16) & 1u);
    return (u16)(r >> 16);
}

// async global->LDS, 16B per lane; LDS dest = wave-uniform base + lane*16
__device__ __forceinline__ void glds16(const u16* g, u16* l) {
    __builtin_amdgcn_global_load_lds((AS1 void*)(g), (AS3 void*)(l), 16, 0, 0);
}

// swizzled LDS element offset for a [row][64] bf16 tile, kq multiple of 8.
__device__ __forceinline__ int swz(int row, int kq) {
    return row * 64 + ((((kq >> 3) ^ row) & 7) << 3);
}

// ---------------------------------------------------------------------------
// Weight convert+transpose: W f32 [K][N] -> WT bf16 [N][K]. Batched over z;
// z < zSplit reads Wa[z], else Wb[z-zSplit].
// ---------------------------------------------------------------------------
__global__ __launch_bounds__(256) void convT2_k(const float* __restrict__ Wa,
        const float* __restrict__ Wb, int zSplit,
        u16* __restrict__ WT, int N, int K)
{
    const int z = blockIdx.z;
    const float* W = (z < zSplit) ? Wa + (size_t)z * K * N
                                  : Wb + (size_t)(z - zSplit) * K * N;
    WT += (size_t)z * K * N;
    const int n0 = blockIdx.x * 64, k0 = blockIdx.y * 64;
    __shared__ float t[64][65];
    const int r = threadIdx.x >> 2;          // 0..63
    const int c = (threadIdx.x & 3) << 4;    // 0,16,32,48
    const float* wp = W + (size_t)(k0 + r) * N + n0 + c;
    #pragma unroll
    for (int q = 0; q < 16; q += 4) {
        float4 f = *(const float4*)(wp + q);
        t[c + q + 0][r] = f.x; t[c + q + 1][r] = f.y;
        t[c + q + 2][r] = f.z; t[c + q + 3][r] = f.w;
    }
    __syncthreads();
    u16* op = WT + (size_t)(n0 + r) * K + k0 + c;
    #pragma unroll
    for (int q = 0; q < 16; q += 8) {
        s8v v;
        #pragma unroll
        for (int j = 0; j < 8; ++j) v[j] = (short)f2bf(t[r][c + q + j]);
        *(s8v*)(op + q) = v;
    }
}

// ---------------------------------------------------------------------------
// src: f32 -> bf16 (srcb) and f32 passthrough (out_share), one read.
// ---------------------------------------------------------------------------
__global__ __launch_bounds__(256) void convsrc_k(const float* __restrict__ in,
        u16* __restrict__ outb, float* __restrict__ outf, int n8)
{
    const int i = blockIdx.x * 256 + threadIdx.x;
    if (i >= n8) return;
    const float4 f0 = ((const float4*)in)[i * 2];
    const float4 f1 = ((const float4*)in)[i * 2 + 1];
    s8v v;
    v[0]=(short)f2bf(f0.x); v[1]=(short)f2bf(f0.y);
    v[2]=(short)f2bf(f0.z); v[3]=(short)f2bf(f0.w);
    v[4]=(short)f2bf(f1.x); v[5]=(short)f2bf(f1.y);
    v[6]=(short)f2bf(f1.z); v[7]=(short)f2bf(f1.w);
    ((s8v*)outb)[i] = v;
    ((float4*)outf)[i * 2]     = f0;
    ((float4*)outf)[i * 2 + 1] = f1;
}

// ---------------------------------------------------------------------------
// Batched bf16 GEMM, 128x128 tile, 8 waves (512 thr), per-wave 32x64 output,
// T2 swizzle, 2-deep counted-vmcnt pipeline, setprio.
// ---------------------------------------------------------------------------
template<int HASDOM>
__global__ __launch_bounds__(512) void gemm_bt128_k(
    const u16* __restrict__ A0, size_t aStrideZ,
    const u16* __restrict__ WT0,
    const float* __restrict__ ebias,
    const float* __restrict__ dbias, const float* __restrict__ dgam,
    const float* __restrict__ dbet,  const float* __restrict__ dmean,
    const float* __restrict__ dvar,  int zdom,
    u16* __restrict__ out0, int M, int N, int K)
{
    const int z = blockIdx.z;
    const u16* A  = A0  + (size_t)z * aStrideZ;
    const u16* WT = WT0 + (size_t)z * N * K;
    u16* out = out0 + (size_t)z * M * N;

    const int n0 = blockIdx.x * 128, m0 = blockIdx.y * 128;
    const int t = threadIdx.x;
    const int w = t >> 6, lane = t & 63;
    const int lq = lane >> 4, lr = lane & 15;
    const int wm = (w >> 1) * 32;      // 4 m-groups of 32 rows
    const int wn = (w & 1) * 64;       // 2 n-groups of 64 cols

    __shared__ __align__(16) u16 As[2 * 128 * 64];
    __shared__ __align__(16) u16 Bs[2 * 128 * 64];

    f4v acc[2][4] = {};

    // staging: thread t covers row (t>>3) (+64 for 2nd issue), chunk (t&7);
    // source chunk pre-swizzled by row&7 (row%8 invariant under +64).
    const int srow = t >> 3;
    const u16* ga = A  + (size_t)(m0 + srow) * K + (((t & 7) ^ (srow & 7)) << 3);
    const u16* gb = WT + (size_t)(n0 + srow) * K + (((t & 7) ^ (srow & 7)) << 3);
    const int wq = w * 512;            // wave LDS base (elems) within a q-section
    const int rowK = 64 * K;

#define STAGE(buf, kk) do { \
    glds16(ga + (kk),        As + (buf) * 8192 + wq); \
    glds16(ga + (kk) + rowK, As + (buf) * 8192 + 4096 + wq); \
    glds16(gb + (kk),        Bs + (buf) * 8192 + wq); \
    glds16(gb + (kk) + rowK, Bs + (buf) * 8192 + 4096 + wq); \
  } while (0)

    const int NT = K >> 6;
    STAGE(0, 0);
    STAGE(1, 64);

    for (int tk = 0; tk < NT; ++tk) {
        if (tk < NT - 1) asm volatile("s_waitcnt vmcnt(4)" ::: "memory");
        else             asm volatile("s_waitcnt vmcnt(0)" ::: "memory");
        __builtin_amdgcn_s_barrier();
        __builtin_amdgcn_sched_barrier(0);

        const u16* Ah = As + (tk & 1) * 8192;
        const u16* Bh = Bs + (tk & 1) * 8192;
        __builtin_amdgcn_s_setprio(1);
        #pragma unroll
        for (int ks = 0; ks < 64; ks += 32) {
            const int kq = ks + (lq << 3);
            s8v a[2], b[4];
            #pragma unroll
            for (int i = 0; i < 2; ++i) a[i] = *(const s8v*)&Ah[swz(wm + i*16 + lr, kq)];
            #pragma unroll
            for (int j = 0; j < 4; ++j) b[j] = *(const s8v*)&Bh[swz(wn + j*16 + lr, kq)];
            #pragma unroll
            for (int i = 0; i < 2; ++i)
                #pragma unroll
                for (int j = 0; j < 4; ++j)
                    acc[i][j] = __builtin_amdgcn_mfma_f32_16x16x32_bf16(a[i], b[j], acc[i][j], 0, 0, 0);
        }
        __builtin_amdgcn_s_setprio(0);
        __builtin_amdgcn_sched_barrier(0);
        __builtin_amdgcn_s_barrier();   // all waves done reading buf[tk&1]

        if (tk + 2 < NT)
            STAGE(tk & 1, (tk + 2) << 6);
    }
#undef STAGE

    float scale[4], shift[4];
    const bool dom = HASDOM && (z == zdom);
    #pragma unroll
    for (int j = 0; j < 4; ++j) {
        const int c = n0 + wn + j * 16 + lr;
        if (dom) {
            const float s = dgam[c] / sqrtf(dvar[c] + 1e-5f);
            scale[j] = s;
            shift[j] = (dbias[c] - dmean[c]) * s + dbet[c];
        } else {
            scale[j] = 1.f;
            shift[j] = ebias[(size_t)z * N + c];
        }
    }
    const int r0 = lq << 2;
    #pragma unroll
    for (int i = 0; i < 2; ++i) {
        #pragma unroll
        for (int r = 0; r < 4; ++r) {
            const int grow = m0 + wm + i * 16 + r0 + r;
            u16* orow = out + (size_t)grow * N + n0 + wn + lr;
            #pragma unroll
            for (int j = 0; j < 4; ++j) {
                float y = fmaf(acc[i][j][r], scale[j], shift[j]);
                if (dom) y = fmaxf(y, 0.f);
                orow[j * 16] = f2bf(y);
            }
        }
    }
}

// ---------------------------------------------------------------------------
// f32-exact split-K GEMM (routing h1 partials). BM=64, BN=128, BK=32,
// 4x8 per thread; conflict-free LDS (interleaved A rows, padded Bs).
// K-order within a slice identical to the previous version (bitwise-same).
// Grid (N/128, M/64, SK).
// ---------------------------------------------------------------------------
__global__ __launch_bounds__(256) void gemm_f32sk_k(
    const float* __restrict__ A, const float* __restrict__ W,
    float* __restrict__ out, int M, int N, int K, int Ks)
{
    const int n0 = blockIdx.x * 128, m0 = blockIdx.y * 64;
    const int kb = blockIdx.z * Ks;
    out += (size_t)blockIdx.z * M * N;
    const int t = threadIdx.x;
    const int tx = t & 15, ty = t >> 4;
    __shared__ float As[64 * 33];
    __shared__ float Bs[32 * 132];
    float acc[4][8] = {};
    const int ar = t >> 2, akc = (t & 3) * 8;   // A stage: row, k-base
    const int bk = t >> 3, bnc = (t & 7) * 16;  // B stage: k, n-base
    for (int kk = kb; kk < kb + Ks; kk += 32) {
        const float* ap = A + (size_t)(m0 + ar) * K + kk + akc;
        const float4 fa0 = *(const float4*)(ap);
        const float4 fa1 = *(const float4*)(ap + 4);
        float* asp = &As[ar * 33 + akc];
        asp[0] = fa0.x; asp[1] = fa0.y; asp[2] = fa0.z; asp[3] = fa0.w;
        asp[4] = fa1.x; asp[5] = fa1.y; asp[6] = fa1.z; asp[7] = fa1.w;
        const float* wp = W + (size_t)(kk + bk) * N + n0 + bnc;
        #pragma unroll
        for (int q = 0; q < 4; ++q)
            *(float4*)&Bs[bk * 132 + bnc + q * 4] = *(const float4*)(wp + q * 4);
        __syncthreads();
        #pragma unroll 8
        for (int kq = 0; kq < 32; ++kq) {
            float a[4];
            #pragma unroll
            for (int i = 0; i < 4; ++i) a[i] = As[(ty + 16 * i) * 33 + kq];
            const float4 b0 = *(const float4*)&Bs[kq * 132 + tx * 4];
            const float4 b1 = *(const float4*)&Bs[kq * 132 + tx * 4 + 64];
            #pragma unroll
            for (int i = 0; i < 4; ++i) {
                acc[i][0] = fmaf(a[i], b0.x, acc[i][0]);
                acc[i][1] = fmaf(a[i], b0.y, acc[i][1]);
                acc[i][2] = fmaf(a[i], b0.z, acc[i][2]);
                acc[i][3] = fmaf(a[i], b0.w, acc[i][3]);
                acc[i][4] = fmaf(a[i], b1.x, acc[i][4]);
                acc[i][5] = fmaf(a[i], b1.y, acc[i][5]);
                acc[i][6] = fmaf(a[i], b1.z, acc[i][6]);
                acc[i][7] = fmaf(a[i], b1.w, acc[i][7]);
            }
        }
        __syncthreads();
    }
    #pragma unroll
    for (int i = 0; i < 4; ++i) {
        float* orow = out + (size_t)(m0 + ty + 16 * i) * N + n0 + tx * 4;
        float4 o0; o0.x = acc[i][0]; o0.y = acc[i][1]; o0.z = acc[i][2]; o0.w = acc[i][3];
        float4 o1; o1.x = acc[i][4]; o1.y = acc[i][5]; o1.z = acc[i][6]; o1.w = acc[i][7];
        *(float4*)orow = o0;
        *(float4*)(orow + 64) = o1;
    }
}

// ---------------------------------------------------------------------------
// Routing h2 GEMM, split-K=4, BN1 precompute fused (per-block k-range).
// ---------------------------------------------------------------------------
__global__ __launch_bounds__(256) void h2gemm_k(
    const float* __restrict__ hp,
    const float* __restrict__ bg1, const float* __restrict__ bbe1,
    const float* __restrict__ bb1, const float* __restrict__ bm1,
    const float* __restrict__ bv1,
    const float* __restrict__ bw2,
    float* __restrict__ out, int B)
{
    const int n0 = blockIdx.x * 64, m0 = blockIdx.y * 64;
    const int kb = blockIdx.z * 128;
    out += (size_t)blockIdx.z * B * 256;
    const size_t sl = (size_t)B * 512;
    const int tid = threadIdx.x;
    const int tx = tid & 15, ty = tid >> 4;
    __shared__ float As[64][65];
    __shared__ float Bs[64][64];
    __shared__ __align__(16) float scl[128], shl[128];
    if (tid < 128) {
        const int k = kb + tid;
        const float sc = bg1[k] / sqrtf(bv1[k] + 1e-5f);
        scl[tid] = sc;
        shl[tid] = (bb1[k] - bm1[k]) * sc + bbe1[k];
    }
    __syncthreads();
    float acc[4][4] = {};
    const int sr = tid >> 2;
    const int sc = (tid & 3) << 4;
    for (int kk = kb; kk < kb + 128; kk += 64) {
        const int kl = kk - kb;
        const float* ap = hp + (size_t)(m0 + sr) * 512 + kk + sc;
        #pragma unroll
        for (int q = 0; q < 4; ++q) {
            const float4 f0 = *(const float4*)(ap + q * 4);
            const float4 f1 = *(const float4*)(ap + sl + q * 4);
            const float4 f2 = *(const float4*)(ap + 2 * sl + q * 4);
            const float4 f3 = *(const float4*)(ap + 3 * sl + q * 4);
            const float4 g = *(const float4*)&scl[kl + sc + q * 4];
            const float4 h = *(const float4*)&shl[kl + sc + q * 4];
            As[sr][sc + q*4 + 0] = fmaxf(fmaf(f0.x + f1.x + f2.x + f3.x, g.x, h.x), 0.f);
            As[sr][sc + q*4 + 1] = fmaxf(fmaf(f0.y + f1.y + f2.y + f3.y, g.y, h.y), 0.f);
            As[sr][sc + q*4 + 2] = fmaxf(fmaf(f0.z + f1.z + f2.z + f3.z, g.z, h.z), 0.f);
            As[sr][sc + q*4 + 3] = fmaxf(fmaf(f0.w + f1.w + f2.w + f3.w, g.w, h.w), 0.f);
        }
        const float* wp = bw2 + (size_t)(kk + sr) * 256 + n0 + sc;
        #pragma unroll
        for (int q = 0; q < 4; ++q)
            *(float4*)&Bs[sr][sc + q*4] = *(const float4*)(wp + q * 4);
        __syncthreads();
        #pragma unroll 4
        for (int kq = 0; kq < 64; ++kq) {
            float a[4], bv[4];
            #pragma unroll
            for (int i = 0; i < 4; ++i) a[i] = As[ty*4 + i][kq];
            #pragma unroll
            for (int j = 0; j < 4; ++j) bv[j] = Bs[kq][tx*4 + j];
            #pragma unroll
            for (int i = 0; i < 4; ++i)
                #pragma unroll
                for (int j = 0; j < 4; ++j)
                    acc[i][j] = fmaf(a[i], bv[j], acc[i][j]);
        }
        __syncthreads();
    }
    #pragma unroll
    for (int j = 0; j < 4; ++j) {
        const int c = n0 + tx*4 + j;
        #pragma unroll
        for (int i = 0; i < 4; ++i)
            out[(size_t)(m0 + ty*4 + i) * 256 + c] = acc[i][j];
    }
}

// ---------------------------------------------------------------------------
// Routing classifier tail.
// ---------------------------------------------------------------------------
__global__ __launch_bounds__(256) void cls_k(
    const float* __restrict__ h2p,
    const float* __restrict__ bg2, const float* __restrict__ bbe2,
    const float* __restrict__ bb2, const float* __restrict__ bm2,
    const float* __restrict__ bv2,
    const float* __restrict__ cw,  const float* __restrict__ cb,
    float* __restrict__ out_src, int* __restrict__ label, int B)
{
    const int b = blockIdx.x * 4 + (threadIdx.x >> 6);
    const int lane = threadIdx.x & 63;
    const size_t sl = (size_t)B * 256;
    const float* hb = h2p + (size_t)b * 256 + lane * 4;
    const float4 v0 = *(const float4*)(hb);
    const float4 v1 = *(const float4*)(hb + sl);
    const float4 v2 = *(const float4*)(hb + 2 * sl);
    const float4 v3 = *(const float4*)(hb + 3 * sl);
    const float4 gv = ((const float4*)bg2)[lane];
    const float4 vv = ((const float4*)bv2)[lane];
    const float4 bbv = ((const float4*)bb2)[lane];
    const float4 bmv = ((const float4*)bm2)[lane];
    const float4 bev = ((const float4*)bbe2)[lane];
    float h[4];
    {
        const float s0 = gv.x / sqrtf(vv.x + 1e-5f);
        const float s1 = gv.y / sqrtf(vv.y + 1e-5f);
        const float s2 = gv.z / sqrtf(vv.z + 1e-5f);
        const float s3 = gv.w / sqrtf(vv.w + 1e-5f);
        h[0] = fmaxf(fmaf(v0.x + v1.x + v2.x + v3.x, s0, (bbv.x - bmv.x) * s0 + bev.x), 0.f);
        h[1] = fmaxf(fmaf(v0.y + v1.y + v2.y + v3.y, s1, (bbv.y - bmv.y) * s1 + bev.y), 0.f);
        h[2] = fmaxf(fmaf(v0.z + v1.z + v2.z + v3.z, s2, (bbv.z - bmv.z) * s2 + bev.z), 0.f);
        h[3] = fmaxf(fmaf(v0.w + v1.w + v2.w + v3.w, s3, (bbv.w - bmv.w) * s3 + bev.w), 0.f);
    }
    float p[8] = {};
    #pragma unroll
    for (int j = 0; j < 4; ++j) {
        const float4 c0 = ((const float4*)cw)[(lane * 4 + j) * 2];
        const float4 c1 = ((const float4*)cw)[(lane * 4 + j) * 2 + 1];
        p[0] = fmaf(h[j], c0.x, p[0]); p[1] = fmaf(h[j], c0.y, p[1]);
        p[2] = fmaf(h[j], c0.z, p[2]); p[3] = fmaf(h[j], c0.w, p[3]);
        p[4] = fmaf(h[j], c1.x, p[4]); p[5] = fmaf(h[j], c1.y, p[5]);
        p[6] = fmaf(h[j], c1.z, p[6]); p[7] = fmaf(h[j], c1.w, p[7]);
    }
    #pragma unroll
    for (int off = 32; off; off >>= 1)
        #pragma unroll
        for (int c = 0; c < 8; ++c) p[c] += __shfl_xor(p[c], off, 64);
    if (lane == 0) {
        float lg[8];
        #pragma unroll
        for (int c = 0; c < 8; ++c) lg[c] = p[c] + cb[c];
        float mx = lg[0]; int am = 0;
        #pragma unroll
        for (int c = 1; c < 8; ++c) if (lg[c] > mx) { mx = lg[c]; am = c; }
        float ssum = 0.f;
        #pragma unroll
        for (int c = 0; c < 8; ++c) ssum += expf(lg[c] - mx);
        const float lse = mx + logf(ssum);
        #pragma unroll
        for (int c = 0; c < 8; ++c) out_src[b * 8 + c] = lg[c] - lse;
        label[b] = am;
    }
}

// ---------------------------------------------------------------------------
// In-place LayerNorm + ReLU, batched over z (grid.y). N=1024.
// ---------------------------------------------------------------------------
template<int N>
__global__ __launch_bounds__(256) void ln_relu_k(u16* __restrict__ Y,
        const float* __restrict__ g, const float* __restrict__ bb)
{
    const int z = blockIdx.y;
    u16* y = Y + ((size_t)z * gridDim.x + blockIdx.x) * N;
    const float* gz = g  + (size_t)z * N;
    const float* bz = bb + (size_t)z * N;
    const int t = threadIdx.x;
    constexpr int C = N >> 8;
    float vals[C];
    ushort4 u = ((const ushort4*)y)[t];
    vals[0] = bf2f(u.x); vals[1] = bf2f(u.y);
    vals[2] = bf2f(u.z); vals[3] = bf2f(u.w);
    float s = 0.f, sq = 0.f;
    #pragma unroll
    for (int i = 0; i < C; ++i) { s += vals[i]; sq += vals[i] * vals[i]; }
    #pragma unroll
    for (int off = 32; off; off >>= 1) {
        s  += __shfl_xor(s,  off, 64);
        sq += __shfl_xor(sq, off, 64);
    }
    __shared__ float rs[4], rq[4];
    if ((t & 63) == 0) { rs[t >> 6] = s; rq[t >> 6] = sq; }
    __syncthreads();
    s  = rs[0] + rs[1] + rs[2] + rs[3];
    sq = rq[0] + rq[1] + rq[2] + rq[3];
    const float inv = 1.f / (float)N;
    const float mu  = s * inv;
    const float var = sq * inv - mu * mu;
    const float rstd = rsqrtf(var + 1e-5f);
    float4 gv = ((const float4*)gz)[t];
    float4 bv = ((const float4*)bz)[t];
    ushort4 o;
    o.x = f2bf(fmaxf((vals[0] - mu) * rstd * gv.x + bv.x, 0.f));
    o.y = f2bf(fmaxf((vals[1] - mu) * rstd * gv.y + bv.y, 0.f));
    o.z = f2bf(fmaxf((vals[2] - mu) * rstd * gv.z + bv.z, 0.f));
    o.w = f2bf(fmaxf((vals[3] - mu) * rstd * gv.w + bv.w, 0.f));
    ((ushort4*)y)[t] = o;
}

// ---------------------------------------------------------------------------
// Selected-expert head: LN(512)+ReLU+512->2 matvec+log_softmax for the ONE
// expert chosen by label[b]. One wave per sample.
// ---------------------------------------------------------------------------
__global__ __launch_bounds__(64) void headsel_k(
    const u16* __restrict__ X,        // [4][B][512] slots zBase..zBase+3
    const int* __restrict__ label,
    const float* __restrict__ eg3, const float* __restrict__ ebe3,
    const float* __restrict__ ew4, const float* __restrict__ eb4,
    int zBase, float* __restrict__ out_sout, int B)
{
    const int b = blockIdx.x;
    const int e = label[b];
    if (e < zBase || e >= zBase + 4) return;
    const int lane = threadIdx.x;
    const u16* x = X + ((size_t)(e - zBase) * B + b) * 512 + lane * 8;
    uint4 raw = *(const uint4*)x;
    const u16* pu = (const u16*)&raw;
    float v[8];
    #pragma unroll
    for (int i = 0; i < 8; ++i) v[i] = bf2f(pu[i]);
    float s = 0.f, sq = 0.f;
    #pragma unroll
    for (int i = 0; i < 8; ++i) { s += v[i]; sq += v[i] * v[i]; }
    #pragma unroll
    for (int off = 32; off; off >>= 1) {
        s  += __shfl_xor(s,  off, 64);
        sq += __shfl_xor(sq, off, 64);
    }
    const float mu = s * (1.f / 512.f);
    const float var = sq * (1.f / 512.f) - mu * mu;
    const float rstd = rsqrtf(var + 1e-5f);
    const float* g  = eg3  + (size_t)e * 512 + lane * 8;
    const float* be = ebe3 + (size_t)e * 512 + lane * 8;
    const float4 g0 = *(const float4*)g,  g1 = *(const float4*)(g + 4);
    const float4 b0 = *(const float4*)be, b1 = *(const float4*)(be + 4);
    float h[8];
    h[0] = fmaxf((v[0]-mu)*rstd*g0.x + b0.x, 0.f);
    h[1] = fmaxf((v[1]-mu)*rstd*g0.y + b0.y, 0.f);
    h[2] = fmaxf((v[2]-mu)*rstd*g0.z + b0.z, 0.f);
    h[3] = fmaxf((v[3]-mu)*rstd*g0.w + b0.w, 0.f);
    h[4] = fmaxf((v[4]-mu)*rstd*g1.x + b1.x, 0.f);
    h[5] = fmaxf((v[5]-mu)*rstd*g1.y + b1.y, 0.f);
    h[6] = fmaxf((v[6]-mu)*rstd*g1.z + b1.z, 0.f);
    h[7] = fmaxf((v[7]-mu)*rstd*g1.w + b1.w, 0.f);
    const float* W = ew4 + (size_t)e * 1024 + lane * 16;
    float p0 = 0.f, p1 = 0.f;
    #pragma unroll
    for (int q = 0; q < 4; ++q) {
        const float4 wv = *(const float4*)(W + q * 4);
        p0 = fmaf(h[q*2],   wv.x, p0); p1 = fmaf(h[q*2],   wv.y, p1);
        p0 = fmaf(h[q*2+1], wv.z, p0); p1 = fmaf(h[q*2+1], wv.w, p1);
    }
    #pragma unroll
    for (int off = 32; off; off >>= 1) {
        p0 += __shfl_xor(p0, off, 64);
        p1 += __shfl_xor(p1, off, 64);
    }
    if (lane == 0) {
        const float l0 = p0 + eb4[e * 2];
        const float l1 = p1 + eb4[e * 2 + 1];
        const float mx = fmaxf(l0, l1);
        const float lse = mx + logf(expf(l0 - mx) + expf(l1 - mx));
        out_sout[b * 2]     = l0 - lse;
        out_sout[b * 2 + 1] = l1 - lse;
    }
}

// ---------------------------------------------------------------------------
// Domain 2-class head + log_softmax (BN+ReLU already applied). 1 wave/row.
// ---------------------------------------------------------------------------
__global__ __launch_bounds__(64) void head2_k(const u16* __restrict__ X,
        const float* __restrict__ W, const float* __restrict__ bias,
        float* __restrict__ out)
{
    const int b = blockIdx.x;
    const int lane = threadIdx.x;
    const u16* x = X + (size_t)b * 512 + lane * 8;
    uint4 raw = *(const uint4*)x;
    const u16* pu = (const u16*)&raw;
    const float* Wz = W + lane * 16;
    float p0 = 0.f, p1 = 0.f;
    #pragma unroll
    for (int q = 0; q < 4; ++q) {
        const float4 wv = *(const float4*)(Wz + q * 4);
        p0 = fmaf(bf2f(pu[q*2]),   wv.x, p0); p1 = fmaf(bf2f(pu[q*2]),   wv.y, p1);
        p0 = fmaf(bf2f(pu[q*2+1]), wv.z, p0); p1 = fmaf(bf2f(pu[q*2+1]), wv.w, p1);
    }
    #pragma unroll
    for (int off = 32; off; off >>= 1) {
        p0 += __shfl_xor(p0, off, 64);
        p1 += __shfl_xor(p1, off, 64);
    }
    if (lane == 0) {
        const float l0 = p0 + bias[0];
        const float l1 = p1 + bias[1];
        const float mx = fmaxf(l0, l1);
        const float lse = mx + logf(expf(l0 - mx) + expf(l1 - mx));
        out[b * 2]     = l0 - lse;
        out[b * 2 + 1] = l1 - lse;
    }
}

// ---------------------------------------------------------------------------

extern "C" void kernel_launch(void* const* d_in, const int* in_sizes, int n_in,
                              void* d_out, int out_size, void* d_ws, size_t ws_size,
                              hipStream_t stream)
{
    const int B = 2048, D = 1280, E = 8;

    const float* src = (const float*)d_in[0];
    const float *bw1 = (const float*)d_in[1],  *bb1 = (const float*)d_in[2],
                *bg1 = (const float*)d_in[3],  *bbe1 = (const float*)d_in[4],
                *bm1 = (const float*)d_in[5],  *bv1 = (const float*)d_in[6];
    const float *bw2 = (const float*)d_in[7],  *bb2 = (const float*)d_in[8],
                *bg2 = (const float*)d_in[9],  *bbe2 = (const float*)d_in[10],
                *bm2 = (const float*)d_in[11], *bv2 = (const float*)d_in[12];
    const float *cw  = (const float*)d_in[13], *cb  = (const float*)d_in[14];
    const float *dw1 = (const float*)d_in[15], *db1 = (const float*)d_in[16],
                *dg1 = (const float*)d_in[17], *dbe1 = (const float*)d_in[18],
                *dm1 = (const float*)d_in[19], *dv1 = (const float*)d_in[20];
    const float *dw2 = (const float*)d_in[21], *db2 = (const float*)d_in[22],
                *dg2 = (const float*)d_in[23], *dbe2 = (const float*)d_in[24],
                *dm2 = (const float*)d_in[25], *dv2 = (const float*)d_in[26];
    const float *dw3 = (const float*)d_in[27], *db3 = (const float*)d_in[28],
                *dg3 = (const float*)d_in[29], *dbe3 = (const float*)d_in[30],
                *dm3 = (const float*)d_in[31], *dv3 = (const float*)d_in[32];
    const float *dw4 = (const float*)d_in[33], *db4 = (const float*)d_in[34];
    const float *ew1 = (const float*)d_in[35], *eb1 = (const float*)d_in[36],
                *eg1 = (const float*)d_in[37], *ebe1 = (const float*)d_in[38];
    const float *ew2 = (const float*)d_in[39], *eb2 = (const float*)d_in[40],
                *eg2 = (const float*)d_in[41], *ebe2 = (const float*)d_in[42];
    const float *ew3 = (const float*)d_in[43], *eb3 = (const float*)d_in[44],
                *eg3 = (const float*)d_in[45], *ebe3 = (const float*)d_in[46];
    const float *ew4 = (const float*)d_in[47], *eb4 = (const float*)d_in[48];

    float* out_src   = (float*)d_out;
    float* out_dclf  = out_src + B * E;
    float* out_sout  = out_dclf + B * 2;
    float* out_share = out_sout + B * 2;

    // ws layout (peak 60.3 MB):
    //   wslot [0, 13.11M)       bf16 JIT weights; during ROUTING holds
    //                           h2p f32 [4][2048][256]
    //   srcb  [13.11M, 18.35M)  bf16 [2048][1280]
    //   acta  [18.35M, 39.32M)  bf16 5 x [2048][1024] (hp f32 [4][2048][512] overlaps)
    //   actb  [39.32M, 60.29M)  bf16 5 x [2048][1024]
    //   label [60.29M, +8K)
    char* ws = (char*)d_ws;
    u16*   wslot = (u16*)ws;
    u16*   srcb  = (u16*)(ws + 13107200);
    u16*   acta  = (u16*)(ws + 18350080);
    u16*   actb  = (u16*)(ws + 39321600);
    int*   label = (int*)(ws + 60293120);
    float* hp    = (float*)(ws + 18350080);   // overlaps acta; dead before experts
    float* h2p   = (float*)(ws);              // overlaps wslot; dead before convT

    const size_t s1024 = (size_t)B * 1024, s512 = (size_t)B * 512;

    // ---- src conversion + share passthrough (single pass) ----
    convsrc_k<<<dim3(B * D / 8 / 256), 256, 0, stream>>>(src, srcb, out_share, B * D / 8);

    // ---- routing ----
    gemm_f32sk_k<<<dim3(512 / 128, B / 64, 4), 256, 0, stream>>>(
        src, bw1, hp, B, 512, D, 320);
    h2gemm_k<<<dim3(256 / 64, B / 64, 4), 256, 0, stream>>>(
        hp, bg1, bbe1, bb1, bm1, bv1, bw2, h2p, B);
    cls_k<<<dim3(B / 4), 256, 0, stream>>>(
        h2p, bg2, bbe2, bb2, bm2, bv2, cw, cb, out_src, label, B);

    // ---- group A: experts 0..3 + domain classifier as z=4 ----
    convT2_k<<<dim3(16, 20, 5), 256, 0, stream>>>(ew1, dw1, 4, wslot, 1024, 1280);
    gemm_bt128_k<1><<<dim3(8, 16, 5), 512, 0, stream>>>(
        srcb, 0, wslot, eb1, db1, dg1, dbe1, dm1, dv1, 4, acta, B, 1024, 1280);
    ln_relu_k<1024><<<dim3(B, 4), 256, 0, stream>>>(acta, eg1, ebe1);

    convT2_k<<<dim3(16, 16, 5), 256, 0, stream>>>(ew2, dw2, 4, wslot, 1024, 1024);
    gemm_bt128_k<1><<<dim3(8, 16, 5), 512, 0, stream>>>(
        acta, s1024, wslot, eb2, db2, dg2, dbe2, dm2, dv2, 4, actb, B, 1024, 1024);
    ln_relu_k<1024><<<dim3(B, 4), 256, 0, stream>>>(actb, eg2, ebe2);

    convT2_k<<<dim3(8, 16, 5), 256, 0, stream>>>(ew3, dw3, 4, wslot, 512, 1024);
    gemm_bt128_k<1><<<dim3(4, 16, 5), 512, 0, stream>>>(
        actb, s1024, wslot, eb3, db3, dg3, dbe3, dm3, dv3, 4, acta, B, 512, 1024);

    headsel_k<<<dim3(B), 64, 0, stream>>>(
        acta, label, eg3, ebe3, ew4, eb4, 0, out_sout, B);
    head2_k<<<dim3(B), 64, 0, stream>>>(
        acta + (size_t)4 * s512, dw4, db4, out_dclf);

    // ---- group B: experts 4..7 ----
    convT2_k<<<dim3(16, 20, 4), 256, 0, stream>>>(
        ew1 + (size_t)4*1280*1024, ew1 + (size_t)4*1280*1024, 4, wslot, 1024, 1280);
    gemm_bt128_k<0><<<dim3(8, 16, 4), 512, 0, stream>>>(
        srcb, 0, wslot, eb1 + (size_t)4*1024,
        nullptr, nullptr, nullptr, nullptr, nullptr, -1, acta, B, 1024, 1280);
    ln_relu_k<1024><<<dim3(B, 4), 256, 0, stream>>>(acta, eg1 + (size_t)4*1024, ebe1 + (size_t)4*1024);

    convT2_k<<<dim3(16, 16, 4), 256, 0, stream>>>(
        ew2 + (size_t)4*1024*1024, ew2 + (size_t)4*1024*1024, 4, wslot, 1024, 1024);
    gemm_bt128_k<0><<<dim3(8, 16, 4), 512, 0, stream>>>(
        acta, s1024, wslot, eb2 + (size_t)4*1024,
        nullptr, nullptr, nullptr, nullptr, nullptr, -1, actb, B, 1024, 1024);
    ln_relu_k<1024><<<dim3(B, 4), 256, 0, stream>>>(actb, eg2 + (size_t)4*1024, ebe2 + (size_t)4*1024);

    convT2_k<<<dim3(8, 16, 4), 256, 0, stream>>>(
        ew3 + (size_t)4*1024*512, ew3 + (size_t)4*1024*512, 4, wslot, 512, 1024);
    gemm_bt128_k<0><<<dim3(4, 16, 4), 512, 0, stream>>>(
        actb, s1024, wslot, eb3 + (size_t)4*512,
        nullptr, nullptr, nullptr, nullptr, nullptr, -1, acta, B, 512, 1024);

    headsel_k<<<dim3(B), 64, 0, stream>>>(
        acta, label, eg3, ebe3, ew4, eb4, 4, out_sout, B);
}